// Round 1
// baseline (2152.917 us; speedup 1.0000x reference)
//
#include <hip/hip_runtime.h>
#include <math.h>

// Problem constants
#define Bb   4
#define Tt   1024
#define Cc   1024
#define Hh   16
#define HKVn 8
#define Nn   64
// M = B*T rows everywhere
#define MT   (Bb*Tt)

// ---------------------------------------------------------------------------
// RoPE cos/sin table: [T][32]
// ---------------------------------------------------------------------------
__global__ void rope_table_kernel(float* __restrict__ cost, float* __restrict__ sint) {
    int t = blockIdx.x;
    int i = threadIdx.x; // 0..31
    float invf = powf(1.0e6f, -(float)i / 32.0f);
    float f = (float)t * invf;
    cost[t * 32 + i] = cosf(f);
    sint[t * 32 + i] = sinf(f);
}

// ---------------------------------------------------------------------------
// fp32 tiled GEMM: C[M,N] = A[M,K] @ B[K,N], row-major, with fused epilogues.
// mode 0: none
// mode 1: tanh
// mode 2: sigmoid
// mode 3: sigmoid(acc + bias[col])
// mode 4: decay: z=acc+bias[col]; w=-softplus(-z)-0.5; out=exp(-exp(w))
// mode 5: v-mix: m=sigmoid(acc+bias[col]); vr=p1[row*512 + kvcol]; vf=p2[row*1024+col];
//         out = vr + (vf-vr)*m     (only used with N==1024)
// Requirements: M % 64 == 0, K % 16 == 0, N % 4 == 0 (partial N tiles guarded).
// ---------------------------------------------------------------------------
__global__ __launch_bounds__(256) void gemm_f32(
    const float* __restrict__ A, const float* __restrict__ B, float* __restrict__ C,
    int M, int N, int K, int mode,
    const float* __restrict__ bias, const float* __restrict__ p1, const float* __restrict__ p2)
{
    __shared__ float As[16][65];   // [k][m]
    __shared__ float Bs[16][68];   // [k][n] (+4 pad keeps float4 alignment)
    int tid = threadIdx.x;
    int bm = blockIdx.y * 64;
    int bn = blockIdx.x * 64;
    int tx = tid & 15, ty = tid >> 4;
    int am = tid >> 2, ak = (tid & 3) << 2;   // A-load: row am, k-offset ak (float4 along k)
    int bk = tid >> 4, bn4 = (tid & 15) << 2; // B-load: k-row bk, col offset bn4 (float4 along n)

    float acc[4][4] = {};

    for (int k0 = 0; k0 < K; k0 += 16) {
        float4 av = *reinterpret_cast<const float4*>(&A[(size_t)(bm + am) * K + k0 + ak]);
        As[ak + 0][am] = av.x; As[ak + 1][am] = av.y;
        As[ak + 2][am] = av.z; As[ak + 3][am] = av.w;

        float4 bv = make_float4(0.f, 0.f, 0.f, 0.f);
        if (bn + bn4 < N)
            bv = *reinterpret_cast<const float4*>(&B[(size_t)(k0 + bk) * N + bn + bn4]);
        *reinterpret_cast<float4*>(&Bs[bk][bn4]) = bv;

        __syncthreads();
        #pragma unroll
        for (int kk = 0; kk < 16; ++kk) {
            float a_[4], b_[4];
            #pragma unroll
            for (int i = 0; i < 4; ++i) a_[i] = As[kk][ty * 4 + i];
            #pragma unroll
            for (int j = 0; j < 4; ++j) b_[j] = Bs[kk][tx * 4 + j];
            #pragma unroll
            for (int i = 0; i < 4; ++i)
                #pragma unroll
                for (int j = 0; j < 4; ++j)
                    acc[i][j] = fmaf(a_[i], b_[j], acc[i][j]);
        }
        __syncthreads();
    }

    #pragma unroll
    for (int i = 0; i < 4; ++i) {
        int row = bm + ty * 4 + i;
        #pragma unroll
        for (int j = 0; j < 4; ++j) {
            int col = bn + tx * 4 + j;
            if (col >= N) continue;
            float v = acc[i][j];
            if (mode == 1) {
                v = tanhf(v);
            } else if (mode == 2) {
                v = 1.f / (1.f + expf(-v));
            } else if (mode == 3) {
                v = 1.f / (1.f + expf(-(v + bias[col])));
            } else if (mode == 4) {
                float z = v + bias[col];
                float t2 = -z;
                float sp = (t2 > 20.f) ? t2 : log1pf(expf(t2));
                float w = -sp - 0.5f;
                v = expf(-expf(w));
            } else if (mode == 5) {
                float m = 1.f / (1.f + expf(-(v + bias[col])));
                float vr = p1[(size_t)row * 512 + ((col >> 7) << 6) + (col & 63)];
                float vf = p2[(size_t)row * 1024 + col];
                v = vr + (vf - vr) * m;
            }
            C[(size_t)row * N + col] = v;
        }
    }
}

// ---------------------------------------------------------------------------
// Per-(b,t,head) RMS-norm over N=64 + RoPE, in place. One wave per block.
// ---------------------------------------------------------------------------
__global__ __launch_bounds__(64) void normrope_kernel(
    float* __restrict__ data, const float* __restrict__ nw,
    const float* __restrict__ cost, const float* __restrict__ sint, int nh)
{
    int bt = blockIdx.x / nh;
    int h  = blockIdx.x % nh;
    int t  = bt & (Tt - 1);
    int lane = threadIdx.x;
    size_t idx = ((size_t)bt * nh + h) * 64 + lane;

    float x = data[idx];
    float ss = x * x;
    #pragma unroll
    for (int m = 1; m < 64; m <<= 1) ss += __shfl_xor(ss, m, 64);
    float xn = x * rsqrtf(ss * (1.f / 64.f) + 1e-6f) * nw[lane];

    float partner = __shfl_xor(xn, 32, 64);
    int fi = lane & 31;
    float c = cost[t * 32 + fi], s = sint[t * 32 + fi];
    float rot = (lane < 32) ? -partner : partner;
    data[idx] = fmaf(xn, c, rot * s);
}

// ---------------------------------------------------------------------------
// WKV-7 scan. One wave per (b,h); lane i owns state row S[i][0..63].
// Fuses: k-normalization, a=-kk, b=kk*a_sig, the r*k*r_k bonus, and y*=g.
// ---------------------------------------------------------------------------
__global__ __launch_bounds__(64) void wkv7_kernel(
    const float* __restrict__ R, const float* __restrict__ K,
    const float* __restrict__ A, const float* __restrict__ D,
    const float* __restrict__ V, const float* __restrict__ G,
    const float* __restrict__ rk, float* __restrict__ Y)
{
    int b = blockIdx.x >> 4;   // / H
    int h = blockIdx.x & 15;   // % H
    int lane = threadIdx.x;

    __shared__ __align__(16) float rs[64], ks[64], as_[64], bs_[64], ds[64];

    float S[64];
    #pragma unroll
    for (int j = 0; j < 64; ++j) S[j] = 0.f;

    float rkl = rk[h * 64 + lane];
    size_t baseC = ((size_t)b * Tt) * Cc + h * 64 + lane;          // + t*1024
    size_t baseK = ((size_t)b * Tt) * (HKVn * Nn) + (h >> 1) * 64 + lane; // + t*512

    float r = R[baseC], k = K[baseK], a = A[baseC], d = D[baseC], v = V[baseC], g = G[baseC];

    for (int t = 0; t < Tt; ++t) {
        // prefetch next step operands
        float rn = 0.f, kn = 0.f, an = 0.f, dn = 0.f, vn = 0.f, gn = 0.f;
        if (t < Tt - 1) {
            size_t oC = baseC + (size_t)(t + 1) * Cc;
            size_t oK = baseK + (size_t)(t + 1) * (HKVn * Nn);
            rn = R[oC]; kn = K[oK]; an = A[oC]; dn = D[oC]; vn = V[oC]; gn = G[oC];
        }

        // kk = k / max(||k||, 1e-12)
        float ss = k * k;
        #pragma unroll
        for (int m = 1; m < 64; m <<= 1) ss += __shfl_xor(ss, m, 64);
        float inv = 1.f / fmaxf(sqrtf(ss), 1e-12f);
        float kkv = k * inv;

        // bonus scalar: sum_j r[j]*k[j]*r_k[h][j]
        float bon = r * k * rkl;
        #pragma unroll
        for (int m = 1; m < 64; m <<= 1) bon += __shfl_xor(bon, m, 64);

        rs[lane] = r; ks[lane] = k; as_[lane] = -kkv; bs_[lane] = kkv * a; ds[lane] = d;
        __syncthreads();

        // sa[i] = sum_j S_old[i][j] * a[j]
        float sa0 = 0.f, sa1 = 0.f, sa2 = 0.f, sa3 = 0.f;
        #pragma unroll
        for (int j = 0; j < 64; j += 4) {
            float4 a4 = *reinterpret_cast<const float4*>(&as_[j]);
            sa0 = fmaf(S[j + 0], a4.x, sa0);
            sa1 = fmaf(S[j + 1], a4.y, sa1);
            sa2 = fmaf(S[j + 2], a4.z, sa2);
            sa3 = fmaf(S[j + 3], a4.w, sa3);
        }
        float sa = (sa0 + sa1) + (sa2 + sa3);

        // S[i][j] = S[i][j]*dec[j] + sa[i]*b[j] + v[i]*k[j];  y[i] = sum_j S[i][j]*r[j]
        float y0 = 0.f, y1 = 0.f, y2 = 0.f, y3 = 0.f;
        #pragma unroll
        for (int j = 0; j < 64; j += 4) {
            float4 d4 = *reinterpret_cast<const float4*>(&ds[j]);
            float4 b4 = *reinterpret_cast<const float4*>(&bs_[j]);
            float4 k4 = *reinterpret_cast<const float4*>(&ks[j]);
            float4 r4 = *reinterpret_cast<const float4*>(&rs[j]);
            S[j + 0] = fmaf(S[j + 0], d4.x, fmaf(sa, b4.x, v * k4.x)); y0 = fmaf(S[j + 0], r4.x, y0);
            S[j + 1] = fmaf(S[j + 1], d4.y, fmaf(sa, b4.y, v * k4.y)); y1 = fmaf(S[j + 1], r4.y, y1);
            S[j + 2] = fmaf(S[j + 2], d4.z, fmaf(sa, b4.z, v * k4.z)); y2 = fmaf(S[j + 2], r4.z, y2);
            S[j + 3] = fmaf(S[j + 3], d4.w, fmaf(sa, b4.w, v * k4.w)); y3 = fmaf(S[j + 3], r4.w, y3);
        }

        float y = ((y0 + y1) + (y2 + y3)) + bon * v;
        y *= g;
        Y[baseC + (size_t)t * Cc] = y;

        __syncthreads();
        r = rn; k = kn; a = an; d = dn; v = vn; g = gn;
    }
}

// ---------------------------------------------------------------------------
// float4 copy for the v_first passthrough output
// ---------------------------------------------------------------------------
__global__ void copy4_kernel(const float4* __restrict__ s, float4* __restrict__ d, int n) {
    int i = blockIdx.x * blockDim.x + threadIdx.x;
    if (i < n) d[i] = s[i];
}

// ---------------------------------------------------------------------------
extern "C" void kernel_launch(void* const* d_in, const int* in_sizes, int n_in,
                              void* d_out, int out_size, void* d_ws, size_t ws_size,
                              hipStream_t stream)
{
    const float* x   = (const float*)d_in[0];
    const float* vfi = (const float*)d_in[1];
    const float* Wr  = (const float*)d_in[2];
    const float* Wk  = (const float*)d_in[3];
    const float* Wv  = (const float*)d_in[4];
    const float* Wo  = (const float*)d_in[5];
    const float* w0  = (const float*)d_in[6];
    const float* w1  = (const float*)d_in[7];
    const float* w2  = (const float*)d_in[8];
    const float* a0  = (const float*)d_in[9];
    const float* a1  = (const float*)d_in[10];
    const float* a2  = (const float*)d_in[11];
    const float* v0  = (const float*)d_in[12];
    const float* v1  = (const float*)d_in[13];
    const float* v2  = (const float*)d_in[14];
    const float* g1  = (const float*)d_in[15];
    const float* g2  = (const float*)d_in[16];
    const float* rk  = (const float*)d_in[17];
    const float* rnw = (const float*)d_in[18];
    const float* knw = (const float*)d_in[19];

    float* ws = (float*)d_ws;
    size_t o = 0;
    float* RRAW = ws + o; o += (size_t)MT * 1024;  // r: raw -> normed+roped in place
    float* KRAW = ws + o; o += (size_t)MT * 512;   // k: raw -> normed+roped in place
    float* VRAW = ws + o; o += (size_t)MT * 512;
    float* XW1  = ws + o; o += (size_t)MT * 64;    // tanh(x@w1)
    float* XA1  = ws + o; o += (size_t)MT * 64;
    float* XV1  = ws + o; o += (size_t)MT * 32;
    float* XG1  = ws + o; o += (size_t)MT * 160;   // sigmoid(x@g1)
    float* DEC  = ws + o; o += (size_t)MT * 1024;  // exp(-exp(w))
    float* AARR = ws + o; o += (size_t)MT * 1024;  // sigmoid(a0 + xa1@a2)
    float* GARR = ws + o; o += (size_t)MT * 1024;  // sigmoid(x@g1)@g2
    float* VFIN = ws + o; o += (size_t)MT * 1024;  // v after GQA-repeat + v_first mixing
    float* YARR = ws + o; o += (size_t)MT * 1024;  // wkv output * g
    float* COS  = ws + o; o += (size_t)Tt * 32;
    float* SIN  = ws + o; o += (size_t)Tt * 32;

    rope_table_kernel<<<dim3(Tt), dim3(32), 0, stream>>>(COS, SIN);

    dim3 blk(256);
    auto grid = [](int N) { return dim3((N + 63) / 64, MT / 64); };

    // stage 1: projections from x
    gemm_f32<<<grid(1024), blk, 0, stream>>>(x, Wr, RRAW, MT, 1024, 1024, 0, nullptr, nullptr, nullptr);
    gemm_f32<<<grid(512),  blk, 0, stream>>>(x, Wk, KRAW, MT, 512,  1024, 0, nullptr, nullptr, nullptr);
    gemm_f32<<<grid(512),  blk, 0, stream>>>(x, Wv, VRAW, MT, 512,  1024, 0, nullptr, nullptr, nullptr);
    gemm_f32<<<grid(64),   blk, 0, stream>>>(x, w1, XW1,  MT, 64,   1024, 1, nullptr, nullptr, nullptr);
    gemm_f32<<<grid(64),   blk, 0, stream>>>(x, a1, XA1,  MT, 64,   1024, 0, nullptr, nullptr, nullptr);
    gemm_f32<<<grid(32),   blk, 0, stream>>>(x, v1, XV1,  MT, 32,   1024, 0, nullptr, nullptr, nullptr);
    gemm_f32<<<grid(160),  blk, 0, stream>>>(x, g1, XG1,  MT, 160,  1024, 2, nullptr, nullptr, nullptr);

    // stage 2: LoRA second matmuls with fused epilogues
    gemm_f32<<<grid(1024), blk, 0, stream>>>(XW1, w2, DEC,  MT, 1024, 64,  4, w0, nullptr, nullptr);
    gemm_f32<<<grid(1024), blk, 0, stream>>>(XA1, a2, AARR, MT, 1024, 64,  3, a0, nullptr, nullptr);
    gemm_f32<<<grid(1024), blk, 0, stream>>>(XV1, v2, VFIN, MT, 1024, 32,  5, v0, VRAW, vfi);
    gemm_f32<<<grid(1024), blk, 0, stream>>>(XG1, g2, GARR, MT, 1024, 160, 0, nullptr, nullptr, nullptr);

    // stage 3: per-head RMS norm + RoPE (in place)
    normrope_kernel<<<dim3(MT * Hh),   dim3(64), 0, stream>>>(RRAW, rnw, COS, SIN, Hh);
    normrope_kernel<<<dim3(MT * HKVn), dim3(64), 0, stream>>>(KRAW, knw, COS, SIN, HKVn);

    // stage 4: sequential WKV scan (fused bonus + gating)
    wkv7_kernel<<<dim3(Bb * Hh), dim3(64), 0, stream>>>(RRAW, KRAW, AARR, DEC, VFIN, GARR, rk, YARR);

    // stage 5: out = (y*g) @ Wo
    gemm_f32<<<grid(1024), blk, 0, stream>>>(YARR, Wo, (float*)d_out, MT, 1024, 1024, 0, nullptr, nullptr, nullptr);

    // stage 6: second tuple output = v_first (unchanged)
    copy4_kernel<<<dim3((MT * 1024 / 4 + 255) / 256), dim3(256), 0, stream>>>(
        (const float4*)vfi, (float4*)((float*)d_out + (size_t)MT * 1024), MT * 1024 / 4);
}

// Round 2
// 1238.085 us; speedup vs baseline: 1.7389x; 1.7389x over previous
//
#include <hip/hip_runtime.h>
#include <math.h>

// Problem constants
#define Bb   4
#define Tt   1024
#define Cc   1024
#define Hh   16
#define HKVn 8
#define Nn   64
#define MT   (Bb*Tt)
#define NC   16      // chunks per sequence
#define CL   64      // chunk length

// ---------------------------------------------------------------------------
// RoPE cos/sin table: [T][32]
// ---------------------------------------------------------------------------
__global__ void rope_table_kernel(float* __restrict__ cost, float* __restrict__ sint) {
    int t = blockIdx.x;
    int i = threadIdx.x; // 0..31
    float invf = powf(1.0e6f, -(float)i / 32.0f);
    float f = (float)t * invf;
    cost[t * 32 + i] = cosf(f);
    sint[t * 32 + i] = sinf(f);
}

// ---------------------------------------------------------------------------
// fp32 tiled GEMM with fused epilogues (unchanged from round 0).
// ---------------------------------------------------------------------------
__global__ __launch_bounds__(256) void gemm_f32(
    const float* __restrict__ A, const float* __restrict__ B, float* __restrict__ C,
    int M, int N, int K, int mode,
    const float* __restrict__ bias, const float* __restrict__ p1, const float* __restrict__ p2)
{
    __shared__ float As[16][65];
    __shared__ float Bs[16][68];
    int tid = threadIdx.x;
    int bm = blockIdx.y * 64;
    int bn = blockIdx.x * 64;
    int tx = tid & 15, ty = tid >> 4;
    int am = tid >> 2, ak = (tid & 3) << 2;
    int bk = tid >> 4, bn4 = (tid & 15) << 2;

    float acc[4][4] = {};

    for (int k0 = 0; k0 < K; k0 += 16) {
        float4 av = *reinterpret_cast<const float4*>(&A[(size_t)(bm + am) * K + k0 + ak]);
        As[ak + 0][am] = av.x; As[ak + 1][am] = av.y;
        As[ak + 2][am] = av.z; As[ak + 3][am] = av.w;

        float4 bv = make_float4(0.f, 0.f, 0.f, 0.f);
        if (bn + bn4 < N)
            bv = *reinterpret_cast<const float4*>(&B[(size_t)(k0 + bk) * N + bn + bn4]);
        *reinterpret_cast<float4*>(&Bs[bk][bn4]) = bv;

        __syncthreads();
        #pragma unroll
        for (int kk = 0; kk < 16; ++kk) {
            float a_[4], b_[4];
            #pragma unroll
            for (int i = 0; i < 4; ++i) a_[i] = As[kk][ty * 4 + i];
            #pragma unroll
            for (int j = 0; j < 4; ++j) b_[j] = Bs[kk][tx * 4 + j];
            #pragma unroll
            for (int i = 0; i < 4; ++i)
                #pragma unroll
                for (int j = 0; j < 4; ++j)
                    acc[i][j] = fmaf(a_[i], b_[j], acc[i][j]);
        }
        __syncthreads();
    }

    #pragma unroll
    for (int i = 0; i < 4; ++i) {
        int row = bm + ty * 4 + i;
        #pragma unroll
        for (int j = 0; j < 4; ++j) {
            int col = bn + tx * 4 + j;
            if (col >= N) continue;
            float v = acc[i][j];
            if (mode == 1) {
                v = tanhf(v);
            } else if (mode == 2) {
                v = 1.f / (1.f + expf(-v));
            } else if (mode == 3) {
                v = 1.f / (1.f + expf(-(v + bias[col])));
            } else if (mode == 4) {
                float z = v + bias[col];
                float t2 = -z;
                float sp = (t2 > 20.f) ? t2 : log1pf(expf(t2));
                float w = -sp - 0.5f;
                v = expf(-expf(w));
            } else if (mode == 5) {
                float m = 1.f / (1.f + expf(-(v + bias[col])));
                float vr = p1[(size_t)row * 512 + ((col >> 7) << 6) + (col & 63)];
                float vf = p2[(size_t)row * 1024 + col];
                v = vr + (vf - vr) * m;
            }
            C[(size_t)row * N + col] = v;
        }
    }
}

// ---------------------------------------------------------------------------
// Per-(b,t,head) RMS-norm over N=64 + RoPE, in place. One wave per block.
// ---------------------------------------------------------------------------
__global__ __launch_bounds__(64) void normrope_kernel(
    float* __restrict__ data, const float* __restrict__ nw,
    const float* __restrict__ cost, const float* __restrict__ sint, int nh)
{
    int bt = blockIdx.x / nh;
    int h  = blockIdx.x % nh;
    int t  = bt & (Tt - 1);
    int lane = threadIdx.x;
    size_t idx = ((size_t)bt * nh + h) * 64 + lane;

    float x = data[idx];
    float ss = x * x;
    #pragma unroll
    for (int m = 1; m < 64; m <<= 1) ss += __shfl_xor(ss, m, 64);
    float xn = x * rsqrtf(ss * (1.f / 64.f) + 1e-6f) * nw[lane];

    float partner = __shfl_xor(xn, 32, 64);
    int fi = lane & 31;
    float c = cost[t * 32 + fi], s = sint[t * 32 + fi];
    float rot = (lane < 32) ? -partner : partner;
    data[idx] = fmaf(xn, c, rot * s);
}

// ---------------------------------------------------------------------------
// prep_ab: hoist state-independent work out of the scan.
// One wave per (b,t,hkv). Computes kk = normalize(k), writes:
//   Ab[b,t,hkv,j]  = -kk[j]
//   Aio[b,t,h,j]   = kk[j] * a_sig[b,t,h,j]   (in place over a_sig, both reps)
//   BON[(b*16+h)*1024 + t] = sum_j r*k*r_k    (both reps)
// ---------------------------------------------------------------------------
__global__ __launch_bounds__(64) void prep_ab(
    const float* __restrict__ Kv, const float* __restrict__ R,
    float* __restrict__ Aio, float* __restrict__ Ab,
    const float* __restrict__ rk, float* __restrict__ BON)
{
    int blk = blockIdx.x;      // bt*8 + hk
    int hk = blk & 7;
    int bt = blk >> 3;
    int b = bt >> 10, t = bt & 1023;
    int lane = threadIdx.x;

    size_t kidx = ((size_t)bt * 8 + hk) * 64 + lane;
    float k = Kv[kidx];
    float ss = k * k;
    #pragma unroll
    for (int m = 1; m < 64; m <<= 1) ss += __shfl_xor(ss, m, 64);
    float kk = k / fmaxf(sqrtf(ss), 1e-12f);
    Ab[kidx] = -kk;

    #pragma unroll
    for (int rep = 0; rep < 2; ++rep) {
        int h = hk * 2 + rep;
        size_t cidx = (size_t)bt * 1024 + h * 64 + lane;
        float asig = Aio[cidx];
        Aio[cidx] = kk * asig;
        float r = R[cidx];
        float bon = r * k * rk[h * 64 + lane];
        #pragma unroll
        for (int m = 1; m < 64; m <<= 1) bon += __shfl_xor(bon, m, 64);
        if (lane == 0) BON[((size_t)(b * 16 + h)) * 1024 + t] = bon;
    }
}

// ---------------------------------------------------------------------------
// wkv_pass1: per-chunk zero-state scan. One wave per (b,h,chunk) = 1024 blocks.
// Lane i owns row i of P (transition product) and Z (zero-init state).
//   P <- P*diag(d) + (P a) b^T ;  Z <- Z*diag(d) + (Z a) b^T + v k^T
// Emits per step: q = P r (for pass3), y0 = Z r (written to Y).
// Emits per chunk: P_L, Z_L.
// ---------------------------------------------------------------------------
__global__ __launch_bounds__(64) void wkv_pass1(
    const float* __restrict__ R, const float* __restrict__ Kv,
    const float* __restrict__ Ab, const float* __restrict__ Bhat,
    const float* __restrict__ Dd, const float* __restrict__ Vv,
    float* __restrict__ Q, float* __restrict__ Y0,
    float* __restrict__ PL, float* __restrict__ ZL)
{
    int blk = blockIdx.x;           // (b*16+h)*16 + c
    int c   = blk & 15;
    int bh  = blk >> 4;
    int h   = bh & 15;
    int b   = bh >> 4;
    int hk  = h >> 1;
    int lane = threadIdx.x;
    int t0 = c * CL;

    __shared__ __align__(16) float as[64], bs[64], dsh[64], ks[64], rs[64];

    float P[64], Z[64];
    #pragma unroll
    for (int j = 0; j < 64; ++j) { P[j] = (j == lane) ? 1.f : 0.f; Z[j] = 0.f; }

    size_t cb = ((size_t)(b * 1024 + t0)) * 1024 + h * 64;
    size_t kb = ((size_t)(b * 1024 + t0)) * 512 + hk * 64;
    size_t qb = (((size_t)bh) * 1024 + t0) * 64;

    float ae = Ab[kb + lane],  be = Bhat[cb + lane], de = Dd[cb + lane],
          ke = Kv[kb + lane],  re = R[cb + lane],    ve = Vv[cb + lane];

    for (int u = 0; u < CL; ++u) {
        as[lane] = ae; bs[lane] = be; dsh[lane] = de; ks[lane] = ke; rs[lane] = re;
        float vcur = ve;
        if (u < CL - 1) {
            size_t oc = cb + (size_t)(u + 1) * 1024;
            size_t ok = kb + (size_t)(u + 1) * 512;
            ae = Ab[ok + lane]; be = Bhat[oc + lane]; de = Dd[oc + lane];
            ke = Kv[ok + lane]; re = R[oc + lane];    ve = Vv[oc + lane];
        }

        // phase A: pa = P.a, za = Z.a
        float pa0 = 0.f, pa1 = 0.f, pa2 = 0.f, pa3 = 0.f;
        float za0 = 0.f, za1 = 0.f, za2 = 0.f, za3 = 0.f;
        #pragma unroll
        for (int jc = 0; jc < 16; ++jc) {
            float4 a4 = *reinterpret_cast<const float4*>(&as[jc * 4]);
            pa0 = fmaf(P[jc*4+0], a4.x, pa0); za0 = fmaf(Z[jc*4+0], a4.x, za0);
            pa1 = fmaf(P[jc*4+1], a4.y, pa1); za1 = fmaf(Z[jc*4+1], a4.y, za1);
            pa2 = fmaf(P[jc*4+2], a4.z, pa2); za2 = fmaf(Z[jc*4+2], a4.z, za2);
            pa3 = fmaf(P[jc*4+3], a4.w, pa3); za3 = fmaf(Z[jc*4+3], a4.w, za3);
        }
        float pa = (pa0 + pa1) + (pa2 + pa3);
        float za = (za0 + za1) + (za2 + za3);

        // phase B: update P, Z; accumulate q = P.r, y0 = Z.r
        float q0 = 0.f, q1 = 0.f, y00 = 0.f, y01 = 0.f;
        #pragma unroll
        for (int jc = 0; jc < 16; ++jc) {
            float4 d4 = *reinterpret_cast<const float4*>(&dsh[jc * 4]);
            float4 b4 = *reinterpret_cast<const float4*>(&bs[jc * 4]);
            float4 k4 = *reinterpret_cast<const float4*>(&ks[jc * 4]);
            float4 r4 = *reinterpret_cast<const float4*>(&rs[jc * 4]);
            P[jc*4+0] = fmaf(P[jc*4+0], d4.x, pa * b4.x);
            Z[jc*4+0] = fmaf(Z[jc*4+0], d4.x, fmaf(za, b4.x, vcur * k4.x));
            q0  = fmaf(P[jc*4+0], r4.x, q0);  y00 = fmaf(Z[jc*4+0], r4.x, y00);
            P[jc*4+1] = fmaf(P[jc*4+1], d4.y, pa * b4.y);
            Z[jc*4+1] = fmaf(Z[jc*4+1], d4.y, fmaf(za, b4.y, vcur * k4.y));
            q1  = fmaf(P[jc*4+1], r4.y, q1);  y01 = fmaf(Z[jc*4+1], r4.y, y01);
            P[jc*4+2] = fmaf(P[jc*4+2], d4.z, pa * b4.z);
            Z[jc*4+2] = fmaf(Z[jc*4+2], d4.z, fmaf(za, b4.z, vcur * k4.z));
            q0  = fmaf(P[jc*4+2], r4.z, q0);  y00 = fmaf(Z[jc*4+2], r4.z, y00);
            P[jc*4+3] = fmaf(P[jc*4+3], d4.w, pa * b4.w);
            Z[jc*4+3] = fmaf(Z[jc*4+3], d4.w, fmaf(za, b4.w, vcur * k4.w));
            q1  = fmaf(P[jc*4+3], r4.w, q1);  y01 = fmaf(Z[jc*4+3], r4.w, y01);
        }
        Q[qb + (size_t)u * 64 + lane] = q0 + q1;
        Y0[cb + (size_t)u * 1024 + lane] = y00 + y01;
    }

    size_t pb = ((size_t)blk) * 4096 + (size_t)lane * 64;
    #pragma unroll
    for (int jc = 0; jc < 16; ++jc) {
        *reinterpret_cast<float4*>(&PL[pb + jc * 4]) =
            make_float4(P[jc*4], P[jc*4+1], P[jc*4+2], P[jc*4+3]);
        *reinterpret_cast<float4*>(&ZL[pb + jc * 4]) =
            make_float4(Z[jc*4], Z[jc*4+1], Z[jc*4+2], Z[jc*4+3]);
    }
}

// ---------------------------------------------------------------------------
// wkv_pass2: sequential chunk-state propagation. One wave per (b,h) = 64 blocks.
// S in LDS; per chunk: export Sstart, then S <- S @ P_c + Z_c (16 steps).
// ---------------------------------------------------------------------------
__global__ __launch_bounds__(64) void wkv_pass2(
    const float* __restrict__ PL, const float* __restrict__ ZL, float* __restrict__ SST)
{
    int bh = blockIdx.x;
    int lane = threadIdx.x;
    __shared__ float Sld[64][65];                 // pad 65: lane-strided col reads 2-way (free)
    __shared__ __align__(16) float Pld[64][68];   // pad 68: 16B-aligned rows for b128 broadcast

    #pragma unroll
    for (int j = 0; j < 64; ++j) Sld[lane][j] = 0.f;
    __syncthreads();

    for (int cc = 0; cc < NC; ++cc) {
        size_t sb = (((size_t)bh) * NC + cc) * 4096 + (size_t)lane * 64;
        #pragma unroll
        for (int jc = 0; jc < 16; ++jc) {
            float4 s4 = make_float4(Sld[lane][jc*4], Sld[lane][jc*4+1],
                                    Sld[lane][jc*4+2], Sld[lane][jc*4+3]);
            *reinterpret_cast<float4*>(&SST[sb + jc * 4]) = s4;
        }
        if (cc == NC - 1) break;

        size_t pb = sb;  // same indexing into PL/ZL
        #pragma unroll
        for (int jc = 0; jc < 16; ++jc) {
            float4 p4 = *reinterpret_cast<const float4*>(&PL[pb + jc * 4]);
            *reinterpret_cast<float4*>(&Pld[lane][jc * 4]) = p4;
        }
        __syncthreads();

        float acc[64];
        #pragma unroll
        for (int jc = 0; jc < 16; ++jc) {
            float4 z4 = *reinterpret_cast<const float4*>(&ZL[pb + jc * 4]);
            acc[jc*4+0] = z4.x; acc[jc*4+1] = z4.y; acc[jc*4+2] = z4.z; acc[jc*4+3] = z4.w;
        }
        for (int m = 0; m < 64; ++m) {
            float sm = Sld[lane][m];
            #pragma unroll
            for (int jc = 0; jc < 16; ++jc) {
                float4 p4 = *reinterpret_cast<const float4*>(&Pld[m][jc * 4]);
                acc[jc*4+0] = fmaf(sm, p4.x, acc[jc*4+0]);
                acc[jc*4+1] = fmaf(sm, p4.y, acc[jc*4+1]);
                acc[jc*4+2] = fmaf(sm, p4.z, acc[jc*4+2]);
                acc[jc*4+3] = fmaf(sm, p4.w, acc[jc*4+3]);
            }
        }
        __syncthreads();
        #pragma unroll
        for (int j = 0; j < 64; ++j) Sld[lane][j] = acc[j];
        __syncthreads();
    }
}

// ---------------------------------------------------------------------------
// wkv_pass3: finalize outputs. One wave per (b,h,chunk) = 1024 blocks.
// y = (y0 + Sstart.q + bon*v) * g, written in place over Y (= y0 buffer).
// ---------------------------------------------------------------------------
__global__ __launch_bounds__(64) void wkv_pass3(
    const float* __restrict__ SST, const float* __restrict__ Q,
    const float* __restrict__ Vv, const float* __restrict__ G,
    const float* __restrict__ BON, float* __restrict__ Y)
{
    int blk = blockIdx.x;   // (b*16+h)*16 + c
    int c = blk & 15, bh = blk >> 4, h = bh & 15, b = bh >> 4;
    int lane = threadIdx.x;
    int t0 = c * CL;

    __shared__ __align__(16) float qs[64];

    float S[64];
    size_t sb = ((size_t)blk) * 4096 + (size_t)lane * 64;
    #pragma unroll
    for (int jc = 0; jc < 16; ++jc) {
        float4 s4 = *reinterpret_cast<const float4*>(&SST[sb + jc * 4]);
        S[jc*4+0] = s4.x; S[jc*4+1] = s4.y; S[jc*4+2] = s4.z; S[jc*4+3] = s4.w;
    }

    size_t cb = ((size_t)(b * 1024 + t0)) * 1024 + h * 64 + lane;
    size_t qb = (((size_t)bh) * 1024 + t0) * 64 + lane;
    size_t bb = ((size_t)bh) * 1024 + t0;

    float qe = Q[qb], y0 = Y[cb], ve = Vv[cb], ge = G[cb], bon = BON[bb];
    for (int u = 0; u < CL; ++u) {
        qs[lane] = qe;
        float y0c = y0, vc = ve, gc = ge, bonc = bon;
        if (u < CL - 1) {
            qe = Q[qb + (size_t)(u + 1) * 64];
            y0 = Y[cb + (size_t)(u + 1) * 1024];
            ve = Vv[cb + (size_t)(u + 1) * 1024];
            ge = G[cb + (size_t)(u + 1) * 1024];
            bon = BON[bb + u + 1];
        }
        float d0 = 0.f, d1 = 0.f, d2 = 0.f, d3 = 0.f;
        #pragma unroll
        for (int jc = 0; jc < 16; ++jc) {
            float4 q4 = *reinterpret_cast<const float4*>(&qs[jc * 4]);
            d0 = fmaf(S[jc*4+0], q4.x, d0);
            d1 = fmaf(S[jc*4+1], q4.y, d1);
            d2 = fmaf(S[jc*4+2], q4.z, d2);
            d3 = fmaf(S[jc*4+3], q4.w, d3);
        }
        float dot = (d0 + d1) + (d2 + d3);
        Y[cb + (size_t)u * 1024] = (y0c + dot + bonc * vc) * gc;
    }
}

// ---------------------------------------------------------------------------
__global__ void copy4_kernel(const float4* __restrict__ s, float4* __restrict__ d, int n) {
    int i = blockIdx.x * blockDim.x + threadIdx.x;
    if (i < n) d[i] = s[i];
}

// ---------------------------------------------------------------------------
extern "C" void kernel_launch(void* const* d_in, const int* in_sizes, int n_in,
                              void* d_out, int out_size, void* d_ws, size_t ws_size,
                              hipStream_t stream)
{
    const float* x   = (const float*)d_in[0];
    const float* vfi = (const float*)d_in[1];
    const float* Wr  = (const float*)d_in[2];
    const float* Wk  = (const float*)d_in[3];
    const float* Wv  = (const float*)d_in[4];
    const float* Wo  = (const float*)d_in[5];
    const float* w0  = (const float*)d_in[6];
    const float* w1  = (const float*)d_in[7];
    const float* w2  = (const float*)d_in[8];
    const float* a0  = (const float*)d_in[9];
    const float* a1  = (const float*)d_in[10];
    const float* a2  = (const float*)d_in[11];
    const float* v0  = (const float*)d_in[12];
    const float* v1  = (const float*)d_in[13];
    const float* v2  = (const float*)d_in[14];
    const float* g1  = (const float*)d_in[15];
    const float* g2  = (const float*)d_in[16];
    const float* rk  = (const float*)d_in[17];
    const float* rnw = (const float*)d_in[18];
    const float* knw = (const float*)d_in[19];

    float* ws = (float*)d_ws;
    size_t o = 0;
    float* RRAW = ws + o; o += (size_t)MT * 1024;  // r (normed+roped); later aliased as SST
    float* KRAW = ws + o; o += (size_t)MT * 512;
    float* VRAW = ws + o; o += (size_t)MT * 512;
    float* XW1  = ws + o; o += (size_t)MT * 64;
    float* XA1  = ws + o; o += (size_t)MT * 64;
    float* XV1  = ws + o; o += (size_t)MT * 32;
    float* XG1  = ws + o; o += (size_t)MT * 160;
    float* DEC  = ws + o; o += (size_t)MT * 1024;
    float* AARR = ws + o; o += (size_t)MT * 1024;  // a_sig, then B-hat (in place)
    float* GARR = ws + o; o += (size_t)MT * 1024;
    float* VFIN = ws + o; o += (size_t)MT * 1024;
    float* YARR = ws + o; o += (size_t)MT * 1024;  // y0, then final y*g (in place)
    float* COS  = ws + o; o += (size_t)Tt * 32;
    float* SIN  = ws + o; o += (size_t)Tt * 32;
    float* ABUF = ws + o; o += (size_t)MT * 512;   // -kk, [b,t,hkv,64]
    float* QBUF = ws + o; o += (size_t)MT * 1024;  // q, [b,h,t,64]
    float* PLB  = ws + o; o += (size_t)1024 * 4096;
    float* ZLB  = ws + o; o += (size_t)1024 * 4096;
    float* BON  = ws + o; o += (size_t)64 * 1024;
    float* SST  = RRAW;                             // alias: RRAW dead after pass1

    rope_table_kernel<<<dim3(Tt), dim3(32), 0, stream>>>(COS, SIN);

    dim3 blk(256);
    auto grid = [](int N) { return dim3((N + 63) / 64, MT / 64); };

    // stage 1: projections from x
    gemm_f32<<<grid(1024), blk, 0, stream>>>(x, Wr, RRAW, MT, 1024, 1024, 0, nullptr, nullptr, nullptr);
    gemm_f32<<<grid(512),  blk, 0, stream>>>(x, Wk, KRAW, MT, 512,  1024, 0, nullptr, nullptr, nullptr);
    gemm_f32<<<grid(512),  blk, 0, stream>>>(x, Wv, VRAW, MT, 512,  1024, 0, nullptr, nullptr, nullptr);
    gemm_f32<<<grid(64),   blk, 0, stream>>>(x, w1, XW1,  MT, 64,   1024, 1, nullptr, nullptr, nullptr);
    gemm_f32<<<grid(64),   blk, 0, stream>>>(x, a1, XA1,  MT, 64,   1024, 0, nullptr, nullptr, nullptr);
    gemm_f32<<<grid(32),   blk, 0, stream>>>(x, v1, XV1,  MT, 32,   1024, 0, nullptr, nullptr, nullptr);
    gemm_f32<<<grid(160),  blk, 0, stream>>>(x, g1, XG1,  MT, 160,  1024, 2, nullptr, nullptr, nullptr);

    // stage 2: LoRA second matmuls with fused epilogues
    gemm_f32<<<grid(1024), blk, 0, stream>>>(XW1, w2, DEC,  MT, 1024, 64,  4, w0, nullptr, nullptr);
    gemm_f32<<<grid(1024), blk, 0, stream>>>(XA1, a2, AARR, MT, 1024, 64,  3, a0, nullptr, nullptr);
    gemm_f32<<<grid(1024), blk, 0, stream>>>(XV1, v2, VFIN, MT, 1024, 32,  5, v0, VRAW, vfi);
    gemm_f32<<<grid(1024), blk, 0, stream>>>(XG1, g2, GARR, MT, 1024, 160, 0, nullptr, nullptr, nullptr);

    // stage 3: per-head RMS norm + RoPE (in place)
    normrope_kernel<<<dim3(MT * Hh),   dim3(64), 0, stream>>>(RRAW, rnw, COS, SIN, Hh);
    normrope_kernel<<<dim3(MT * HKVn), dim3(64), 0, stream>>>(KRAW, knw, COS, SIN, HKVn);

    // stage 4: hoist reductions out of the scan
    prep_ab<<<dim3(MT * HKVn), dim3(64), 0, stream>>>(KRAW, RRAW, AARR, ABUF, rk, BON);

    // stage 5: chunk-parallel WKV scan
    wkv_pass1<<<dim3(Bb * Hh * NC), dim3(64), 0, stream>>>(
        RRAW, KRAW, ABUF, AARR, DEC, VFIN, QBUF, YARR, PLB, ZLB);
    wkv_pass2<<<dim3(Bb * Hh), dim3(64), 0, stream>>>(PLB, ZLB, SST);
    wkv_pass3<<<dim3(Bb * Hh * NC), dim3(64), 0, stream>>>(SST, QBUF, VFIN, GARR, BON, YARR);

    // stage 6: out = (y*g) @ Wo
    gemm_f32<<<grid(1024), blk, 0, stream>>>(YARR, Wo, (float*)d_out, MT, 1024, 1024, 0, nullptr, nullptr, nullptr);

    // stage 7: second tuple output = v_first (unchanged)
    copy4_kernel<<<dim3((MT * 1024 / 4 + 255) / 256), dim3(256), 0, stream>>>(
        (const float4*)vfi, (float4*)((float*)d_out + (size_t)MT * 1024), MT * 1024 / 4);
}

// Round 3
// 749.534 us; speedup vs baseline: 2.8723x; 1.6518x over previous
//
#include <hip/hip_runtime.h>
#include <math.h>
#include <stdint.h>

// Problem constants
#define Bb   4
#define Tt   1024
#define Cc   1024
#define Hh   16
#define HKVn 8
#define Nn   64
#define MT   (Bb*Tt)
#define NC   16      // chunks per sequence
#define CL   64      // chunk length

typedef __bf16 bf16x8_t __attribute__((ext_vector_type(8)));
typedef float  f32x4_t  __attribute__((ext_vector_type(4)));

__device__ __forceinline__ uint16_t f2bf(float f) {
    uint32_t u = __float_as_uint(f);
    uint32_t r = (u + 0x7fffu + ((u >> 16) & 1u)) >> 16;
    return (uint16_t)r;
}

// ---------------------------------------------------------------------------
// RoPE cos/sin table: [T][32]
// ---------------------------------------------------------------------------
__global__ void rope_table_kernel(float* __restrict__ cost, float* __restrict__ sint) {
    int t = blockIdx.x;
    int i = threadIdx.x; // 0..31
    float invf = powf(1.0e6f, -(float)i / 32.0f);
    float f = (float)t * invf;
    cost[t * 32 + i] = cosf(f);
    sint[t * 32 + i] = sinf(f);
}

// ---------------------------------------------------------------------------
// fp32 -> bf16 flat convert (n multiple of 4)
// ---------------------------------------------------------------------------
__global__ __launch_bounds__(256) void f32_to_bf16_kernel(
    const float* __restrict__ in, uint16_t* __restrict__ out, int n4)
{
    int i = blockIdx.x * blockDim.x + threadIdx.x;
    if (i >= n4) return;
    float4 v = reinterpret_cast<const float4*>(in)[i];
    ushort4 o;
    o.x = f2bf(v.x); o.y = f2bf(v.y); o.z = f2bf(v.z); o.w = f2bf(v.w);
    reinterpret_cast<ushort4*>(out)[i] = o;
}

// ---------------------------------------------------------------------------
// Weight transpose + convert: W[K][N] fp32 -> Wt[N][K] bf16. 32x32 tiles.
// ---------------------------------------------------------------------------
__global__ __launch_bounds__(256) void transpose_bf16_kernel(
    const float* __restrict__ W, uint16_t* __restrict__ Wt, int K, int N)
{
    __shared__ float tile[32][33];
    int n0 = blockIdx.x * 32, k0 = blockIdx.y * 32;
    int tx = threadIdx.x & 31, ty = threadIdx.x >> 5; // 32 x 8
    #pragma unroll
    for (int i = 0; i < 32; i += 8) {
        int k = k0 + ty + i, n = n0 + tx;
        tile[ty + i][tx] = (k < K && n < N) ? W[(size_t)k * N + n] : 0.f;
    }
    __syncthreads();
    #pragma unroll
    for (int i = 0; i < 32; i += 8) {
        int n = n0 + ty + i, k = k0 + tx;
        if (n < N && k < K) Wt[(size_t)n * K + k] = f2bf(tile[tx][ty + i]);
    }
}

// ---------------------------------------------------------------------------
// bf16 MFMA GEMM: C[M][N](fp32) = A[M][K](bf16,row-major) @ Bt[N][K](bf16)^T
// 128x128 tile, BK=64, 4 waves (2x2), 16x16x32 MFMA.
// global_load_lds width-16 staging, linear LDS + inverse-swizzled source,
// XOR-swizzled ds_read_b128 (st-style swizzle: byte ^= (row&7)<<4).
// Requires M%128==0, K%64==0. N arbitrary (guarded).
// mode 0: none; 1: tanh; 2: sigmoid.
// ---------------------------------------------------------------------------
__global__ __launch_bounds__(256) void gemm_bf16(
    const uint16_t* __restrict__ A, const uint16_t* __restrict__ Bt,
    float* __restrict__ C, int M, int N, int K, int mode)
{
    __shared__ __align__(16) uint16_t As[128 * 64];
    __shared__ __align__(16) uint16_t Bs[128 * 64];
    int tid  = threadIdx.x;
    int lane = tid & 63, wid = tid >> 6;
    int wm = (wid >> 1) * 64, wn = (wid & 1) * 64;
    int bm = blockIdx.y * 128, bn = blockIdx.x * 128;

    f32x4_t acc[4][4];
    #pragma unroll
    for (int i = 0; i < 4; ++i)
        #pragma unroll
        for (int j = 0; j < 4; ++j)
            #pragma unroll
            for (int e = 0; e < 4; ++e) acc[i][j][e] = 0.f;

    // precompute per-lane staging parameters (4 chunks of 256 lanes)
    int rowS[4], kbS[4];
    #pragma unroll
    for (int i = 0; i < 4; ++i) {
        int d = (i * 256 + tid) * 16;        // linear LDS dest byte
        int row = d >> 7;                    // tile row (128B per row)
        int kb = (d & 127) ^ ((row & 7) << 4); // inverse-swizzled byte-in-row
        rowS[i] = row; kbS[i] = kb >> 1;     // element offset in row
    }

    for (int k0 = 0; k0 < K; k0 += 64) {
        #pragma unroll
        for (int i = 0; i < 4; ++i) {
            const uint16_t* srcA = A + (size_t)(bm + rowS[i]) * K + k0 + kbS[i];
            uint16_t* ldsA = As + (i * 256 + wid * 64) * 8;
            __builtin_amdgcn_global_load_lds(
                (const __attribute__((address_space(1))) uint32_t*)srcA,
                (__attribute__((address_space(3))) uint32_t*)ldsA, 16, 0, 0);
            int nr = bn + rowS[i];
            const uint16_t* srcB = Bt + (size_t)(nr < N ? nr : 0) * K + k0 + kbS[i];
            uint16_t* ldsB = Bs + (i * 256 + wid * 64) * 8;
            __builtin_amdgcn_global_load_lds(
                (const __attribute__((address_space(1))) uint32_t*)srcB,
                (__attribute__((address_space(3))) uint32_t*)ldsB, 16, 0, 0);
        }
        __syncthreads();

        #pragma unroll
        for (int kk = 0; kk < 64; kk += 32) {
            int fb = (kk + ((lane >> 4) << 3)) << 1;  // byte offset of 16B frag in row
            bf16x8_t af[4], bfr[4];
            #pragma unroll
            for (int i = 0; i < 4; ++i) {
                int row = wm + i * 16 + (lane & 15);
                int byteA = (row << 7) + (fb ^ ((row & 7) << 4));
                af[i] = *reinterpret_cast<const bf16x8_t*>(
                    reinterpret_cast<const char*>(As) + byteA);
                int col = wn + i * 16 + (lane & 15);
                int byteB = (col << 7) + (fb ^ ((col & 7) << 4));
                bfr[i] = *reinterpret_cast<const bf16x8_t*>(
                    reinterpret_cast<const char*>(Bs) + byteB);
            }
            #pragma unroll
            for (int i = 0; i < 4; ++i)
                #pragma unroll
                for (int j = 0; j < 4; ++j)
                    acc[i][j] = __builtin_amdgcn_mfma_f32_16x16x32_bf16(
                        af[i], bfr[j], acc[i][j], 0, 0, 0);
        }
        __syncthreads();
    }

    // epilogue: C/D layout col=lane&15, row=(lane>>4)*4+reg
    #pragma unroll
    for (int i = 0; i < 4; ++i) {
        int row0 = bm + wm + i * 16 + ((lane >> 4) << 2);
        #pragma unroll
        for (int j = 0; j < 4; ++j) {
            int col = bn + wn + j * 16 + (lane & 15);
            if (col >= N) continue;
            #pragma unroll
            for (int rg = 0; rg < 4; ++rg) {
                float v = acc[i][j][rg];
                if (mode == 1) v = tanhf(v);
                else if (mode == 2) v = 1.f / (1.f + expf(-v));
                C[(size_t)(row0 + rg) * N + col] = v;
            }
        }
    }
}

// ---------------------------------------------------------------------------
// fp32 tiled GEMM with fused epilogues (stage-2 LoRA, small K).
// ---------------------------------------------------------------------------
__global__ __launch_bounds__(256) void gemm_f32(
    const float* __restrict__ A, const float* __restrict__ B, float* __restrict__ C,
    int M, int N, int K, int mode,
    const float* __restrict__ bias, const float* __restrict__ p1, const float* __restrict__ p2)
{
    __shared__ float As[16][65];
    __shared__ float Bs[16][68];
    int tid = threadIdx.x;
    int bm = blockIdx.y * 64;
    int bn = blockIdx.x * 64;
    int tx = tid & 15, ty = tid >> 4;
    int am = tid >> 2, ak = (tid & 3) << 2;
    int bk = tid >> 4, bn4 = (tid & 15) << 2;

    float acc[4][4] = {};

    for (int k0 = 0; k0 < K; k0 += 16) {
        float4 av = *reinterpret_cast<const float4*>(&A[(size_t)(bm + am) * K + k0 + ak]);
        As[ak + 0][am] = av.x; As[ak + 1][am] = av.y;
        As[ak + 2][am] = av.z; As[ak + 3][am] = av.w;

        float4 bv = make_float4(0.f, 0.f, 0.f, 0.f);
        if (bn + bn4 < N)
            bv = *reinterpret_cast<const float4*>(&B[(size_t)(k0 + bk) * N + bn + bn4]);
        *reinterpret_cast<float4*>(&Bs[bk][bn4]) = bv;

        __syncthreads();
        #pragma unroll
        for (int kk = 0; kk < 16; ++kk) {
            float a_[4], b_[4];
            #pragma unroll
            for (int i = 0; i < 4; ++i) a_[i] = As[kk][ty * 4 + i];
            #pragma unroll
            for (int j = 0; j < 4; ++j) b_[j] = Bs[kk][tx * 4 + j];
            #pragma unroll
            for (int i = 0; i < 4; ++i)
                #pragma unroll
                for (int j = 0; j < 4; ++j)
                    acc[i][j] = fmaf(a_[i], b_[j], acc[i][j]);
        }
        __syncthreads();
    }

    #pragma unroll
    for (int i = 0; i < 4; ++i) {
        int row = bm + ty * 4 + i;
        #pragma unroll
        for (int j = 0; j < 4; ++j) {
            int col = bn + tx * 4 + j;
            if (col >= N) continue;
            float v = acc[i][j];
            if (mode == 1) {
                v = tanhf(v);
            } else if (mode == 2) {
                v = 1.f / (1.f + expf(-v));
            } else if (mode == 3) {
                v = 1.f / (1.f + expf(-(v + bias[col])));
            } else if (mode == 4) {
                float z = v + bias[col];
                float t2 = -z;
                float sp = (t2 > 20.f) ? t2 : log1pf(expf(t2));
                float w = -sp - 0.5f;
                v = expf(-expf(w));
            } else if (mode == 5) {
                float m = 1.f / (1.f + expf(-(v + bias[col])));
                float vr = p1[(size_t)row * 512 + ((col >> 7) << 6) + (col & 63)];
                float vf = p2[(size_t)row * 1024 + col];
                v = vr + (vf - vr) * m;
            }
            C[(size_t)row * N + col] = v;
        }
    }
}

// ---------------------------------------------------------------------------
// Per-(b,t,head) RMS-norm over N=64 + RoPE, in place. One wave per block.
// ---------------------------------------------------------------------------
__global__ __launch_bounds__(64) void normrope_kernel(
    float* __restrict__ data, const float* __restrict__ nw,
    const float* __restrict__ cost, const float* __restrict__ sint, int nh)
{
    int bt = blockIdx.x / nh;
    int h  = blockIdx.x % nh;
    int t  = bt & (Tt - 1);
    int lane = threadIdx.x;
    size_t idx = ((size_t)bt * nh + h) * 64 + lane;

    float x = data[idx];
    float ss = x * x;
    #pragma unroll
    for (int m = 1; m < 64; m <<= 1) ss += __shfl_xor(ss, m, 64);
    float xn = x * rsqrtf(ss * (1.f / 64.f) + 1e-6f) * nw[lane];

    float partner = __shfl_xor(xn, 32, 64);
    int fi = lane & 31;
    float c = cost[t * 32 + fi], s = sint[t * 32 + fi];
    float rot = (lane < 32) ? -partner : partner;
    data[idx] = fmaf(xn, c, rot * s);
}

// ---------------------------------------------------------------------------
// prep_ab: hoist state-independent work out of the scan.
// ---------------------------------------------------------------------------
__global__ __launch_bounds__(64) void prep_ab(
    const float* __restrict__ Kv, const float* __restrict__ R,
    float* __restrict__ Aio, float* __restrict__ Ab,
    const float* __restrict__ rk, float* __restrict__ BON)
{
    int blk = blockIdx.x;      // bt*8 + hk
    int hk = blk & 7;
    int bt = blk >> 3;
    int b = bt >> 10, t = bt & 1023;
    int lane = threadIdx.x;

    size_t kidx = ((size_t)bt * 8 + hk) * 64 + lane;
    float k = Kv[kidx];
    float ss = k * k;
    #pragma unroll
    for (int m = 1; m < 64; m <<= 1) ss += __shfl_xor(ss, m, 64);
    float kk = k / fmaxf(sqrtf(ss), 1e-12f);
    Ab[kidx] = -kk;

    #pragma unroll
    for (int rep = 0; rep < 2; ++rep) {
        int h = hk * 2 + rep;
        size_t cidx = (size_t)bt * 1024 + h * 64 + lane;
        float asig = Aio[cidx];
        Aio[cidx] = kk * asig;
        float r = R[cidx];
        float bon = r * k * rk[h * 64 + lane];
        #pragma unroll
        for (int m = 1; m < 64; m <<= 1) bon += __shfl_xor(bon, m, 64);
        if (lane == 0) BON[((size_t)(b * 16 + h)) * 1024 + t] = bon;
    }
}

// ---------------------------------------------------------------------------
// wkv_pass1: per-chunk zero-state scan. One wave per (b,h,chunk) = 1024 blocks.
// ---------------------------------------------------------------------------
__global__ __launch_bounds__(64) void wkv_pass1(
    const float* __restrict__ R, const float* __restrict__ Kv,
    const float* __restrict__ Ab, const float* __restrict__ Bhat,
    const float* __restrict__ Dd, const float* __restrict__ Vv,
    float* __restrict__ Q, float* __restrict__ Y0,
    float* __restrict__ PL, float* __restrict__ ZL)
{
    int blk = blockIdx.x;           // (b*16+h)*16 + c
    int c   = blk & 15;
    int bh  = blk >> 4;
    int h   = bh & 15;
    int b   = bh >> 4;
    int hk  = h >> 1;
    int lane = threadIdx.x;
    int t0 = c * CL;

    __shared__ __align__(16) float as[64], bs[64], dsh[64], ks[64], rs[64];

    float P[64], Z[64];
    #pragma unroll
    for (int j = 0; j < 64; ++j) { P[j] = (j == lane) ? 1.f : 0.f; Z[j] = 0.f; }

    size_t cb = ((size_t)(b * 1024 + t0)) * 1024 + h * 64;
    size_t kb = ((size_t)(b * 1024 + t0)) * 512 + hk * 64;
    size_t qb = (((size_t)bh) * 1024 + t0) * 64;

    float ae = Ab[kb + lane],  be = Bhat[cb + lane], de = Dd[cb + lane],
          ke = Kv[kb + lane],  re = R[cb + lane],    ve = Vv[cb + lane];

    for (int u = 0; u < CL; ++u) {
        as[lane] = ae; bs[lane] = be; dsh[lane] = de; ks[lane] = ke; rs[lane] = re;
        float vcur = ve;
        if (u < CL - 1) {
            size_t oc = cb + (size_t)(u + 1) * 1024;
            size_t ok = kb + (size_t)(u + 1) * 512;
            ae = Ab[ok + lane]; be = Bhat[oc + lane]; de = Dd[oc + lane];
            ke = Kv[ok + lane]; re = R[oc + lane];    ve = Vv[oc + lane];
        }

        float pa0 = 0.f, pa1 = 0.f, pa2 = 0.f, pa3 = 0.f;
        float za0 = 0.f, za1 = 0.f, za2 = 0.f, za3 = 0.f;
        #pragma unroll
        for (int jc = 0; jc < 16; ++jc) {
            float4 a4 = *reinterpret_cast<const float4*>(&as[jc * 4]);
            pa0 = fmaf(P[jc*4+0], a4.x, pa0); za0 = fmaf(Z[jc*4+0], a4.x, za0);
            pa1 = fmaf(P[jc*4+1], a4.y, pa1); za1 = fmaf(Z[jc*4+1], a4.y, za1);
            pa2 = fmaf(P[jc*4+2], a4.z, pa2); za2 = fmaf(Z[jc*4+2], a4.z, za2);
            pa3 = fmaf(P[jc*4+3], a4.w, pa3); za3 = fmaf(Z[jc*4+3], a4.w, za3);
        }
        float pa = (pa0 + pa1) + (pa2 + pa3);
        float za = (za0 + za1) + (za2 + za3);

        float q0 = 0.f, q1 = 0.f, y00 = 0.f, y01 = 0.f;
        #pragma unroll
        for (int jc = 0; jc < 16; ++jc) {
            float4 d4 = *reinterpret_cast<const float4*>(&dsh[jc * 4]);
            float4 b4 = *reinterpret_cast<const float4*>(&bs[jc * 4]);
            float4 k4 = *reinterpret_cast<const float4*>(&ks[jc * 4]);
            float4 r4 = *reinterpret_cast<const float4*>(&rs[jc * 4]);
            P[jc*4+0] = fmaf(P[jc*4+0], d4.x, pa * b4.x);
            Z[jc*4+0] = fmaf(Z[jc*4+0], d4.x, fmaf(za, b4.x, vcur * k4.x));
            q0  = fmaf(P[jc*4+0], r4.x, q0);  y00 = fmaf(Z[jc*4+0], r4.x, y00);
            P[jc*4+1] = fmaf(P[jc*4+1], d4.y, pa * b4.y);
            Z[jc*4+1] = fmaf(Z[jc*4+1], d4.y, fmaf(za, b4.y, vcur * k4.y));
            q1  = fmaf(P[jc*4+1], r4.y, q1);  y01 = fmaf(Z[jc*4+1], r4.y, y01);
            P[jc*4+2] = fmaf(P[jc*4+2], d4.z, pa * b4.z);
            Z[jc*4+2] = fmaf(Z[jc*4+2], d4.z, fmaf(za, b4.z, vcur * k4.z));
            q0  = fmaf(P[jc*4+2], r4.z, q0);  y00 = fmaf(Z[jc*4+2], r4.z, y00);
            P[jc*4+3] = fmaf(P[jc*4+3], d4.w, pa * b4.w);
            Z[jc*4+3] = fmaf(Z[jc*4+3], d4.w, fmaf(za, b4.w, vcur * k4.w));
            q1  = fmaf(P[jc*4+3], r4.w, q1);  y01 = fmaf(Z[jc*4+3], r4.w, y01);
        }
        Q[qb + (size_t)u * 64 + lane] = q0 + q1;
        Y0[cb + (size_t)u * 1024 + lane] = y00 + y01;
    }

    size_t pb = ((size_t)blk) * 4096 + (size_t)lane * 64;
    #pragma unroll
    for (int jc = 0; jc < 16; ++jc) {
        *reinterpret_cast<float4*>(&PL[pb + jc * 4]) =
            make_float4(P[jc*4], P[jc*4+1], P[jc*4+2], P[jc*4+3]);
        *reinterpret_cast<float4*>(&ZL[pb + jc * 4]) =
            make_float4(Z[jc*4], Z[jc*4+1], Z[jc*4+2], Z[jc*4+3]);
    }
}

// ---------------------------------------------------------------------------
// wkv_pass2: sequential chunk-state propagation. One wave per (b,h) = 64 blocks.
// ---------------------------------------------------------------------------
__global__ __launch_bounds__(64) void wkv_pass2(
    const float* __restrict__ PL, const float* __restrict__ ZL, float* __restrict__ SST)
{
    int bh = blockIdx.x;
    int lane = threadIdx.x;
    __shared__ float Sld[64][65];
    __shared__ __align__(16) float Pld[64][68];

    #pragma unroll
    for (int j = 0; j < 64; ++j) Sld[lane][j] = 0.f;
    __syncthreads();

    for (int cc = 0; cc < NC; ++cc) {
        size_t sb = (((size_t)bh) * NC + cc) * 4096 + (size_t)lane * 64;
        #pragma unroll
        for (int jc = 0; jc < 16; ++jc) {
            float4 s4 = make_float4(Sld[lane][jc*4], Sld[lane][jc*4+1],
                                    Sld[lane][jc*4+2], Sld[lane][jc*4+3]);
            *reinterpret_cast<float4*>(&SST[sb + jc * 4]) = s4;
        }
        if (cc == NC - 1) break;

        size_t pb = sb;
        #pragma unroll
        for (int jc = 0; jc < 16; ++jc) {
            float4 p4 = *reinterpret_cast<const float4*>(&PL[pb + jc * 4]);
            *reinterpret_cast<float4*>(&Pld[lane][jc * 4]) = p4;
        }
        __syncthreads();

        float acc[64];
        #pragma unroll
        for (int jc = 0; jc < 16; ++jc) {
            float4 z4 = *reinterpret_cast<const float4*>(&ZL[pb + jc * 4]);
            acc[jc*4+0] = z4.x; acc[jc*4+1] = z4.y; acc[jc*4+2] = z4.z; acc[jc*4+3] = z4.w;
        }
        for (int m = 0; m < 64; ++m) {
            float sm = Sld[lane][m];
            #pragma unroll
            for (int jc = 0; jc < 16; ++jc) {
                float4 p4 = *reinterpret_cast<const float4*>(&Pld[m][jc * 4]);
                acc[jc*4+0] = fmaf(sm, p4.x, acc[jc*4+0]);
                acc[jc*4+1] = fmaf(sm, p4.y, acc[jc*4+1]);
                acc[jc*4+2] = fmaf(sm, p4.z, acc[jc*4+2]);
                acc[jc*4+3] = fmaf(sm, p4.w, acc[jc*4+3]);
            }
        }
        __syncthreads();
        #pragma unroll
        for (int j = 0; j < 64; ++j) Sld[lane][j] = acc[j];
        __syncthreads();
    }
}

// ---------------------------------------------------------------------------
// wkv_pass3: y = (y0 + Sstart.q + bon*v) * g -> bf16 output for the Wo GEMM.
// ---------------------------------------------------------------------------
__global__ __launch_bounds__(64) void wkv_pass3(
    const float* __restrict__ SST, const float* __restrict__ Q,
    const float* __restrict__ Vv, const float* __restrict__ G,
    const float* __restrict__ BON, const float* __restrict__ Y0,
    uint16_t* __restrict__ Yb)
{
    int blk = blockIdx.x;   // (b*16+h)*16 + c
    int c = blk & 15, bh = blk >> 4, h = bh & 15, b = bh >> 4;
    int lane = threadIdx.x;
    int t0 = c * CL;

    __shared__ __align__(16) float qs[64];

    float S[64];
    size_t sb = ((size_t)blk) * 4096 + (size_t)lane * 64;
    #pragma unroll
    for (int jc = 0; jc < 16; ++jc) {
        float4 s4 = *reinterpret_cast<const float4*>(&SST[sb + jc * 4]);
        S[jc*4+0] = s4.x; S[jc*4+1] = s4.y; S[jc*4+2] = s4.z; S[jc*4+3] = s4.w;
    }

    size_t cb = ((size_t)(b * 1024 + t0)) * 1024 + h * 64 + lane;
    size_t qb = (((size_t)bh) * 1024 + t0) * 64 + lane;
    size_t bb = ((size_t)bh) * 1024 + t0;

    float qe = Q[qb], y0 = Y0[cb], ve = Vv[cb], ge = G[cb], bon = BON[bb];
    for (int u = 0; u < CL; ++u) {
        qs[lane] = qe;
        float y0c = y0, vc = ve, gc = ge, bonc = bon;
        if (u < CL - 1) {
            qe = Q[qb + (size_t)(u + 1) * 64];
            y0 = Y0[cb + (size_t)(u + 1) * 1024];
            ve = Vv[cb + (size_t)(u + 1) * 1024];
            ge = G[cb + (size_t)(u + 1) * 1024];
            bon = BON[bb + u + 1];
        }
        float d0 = 0.f, d1 = 0.f, d2 = 0.f, d3 = 0.f;
        #pragma unroll
        for (int jc = 0; jc < 16; ++jc) {
            float4 q4 = *reinterpret_cast<const float4*>(&qs[jc * 4]);
            d0 = fmaf(S[jc*4+0], q4.x, d0);
            d1 = fmaf(S[jc*4+1], q4.y, d1);
            d2 = fmaf(S[jc*4+2], q4.z, d2);
            d3 = fmaf(S[jc*4+3], q4.w, d3);
        }
        float dot = (d0 + d1) + (d2 + d3);
        Yb[cb + (size_t)u * 1024] = f2bf((y0c + dot + bonc * vc) * gc);
    }
}

// ---------------------------------------------------------------------------
__global__ void copy4_kernel(const float4* __restrict__ s, float4* __restrict__ d, int n) {
    int i = blockIdx.x * blockDim.x + threadIdx.x;
    if (i < n) d[i] = s[i];
}

// ---------------------------------------------------------------------------
extern "C" void kernel_launch(void* const* d_in, const int* in_sizes, int n_in,
                              void* d_out, int out_size, void* d_ws, size_t ws_size,
                              hipStream_t stream)
{
    const float* x   = (const float*)d_in[0];
    const float* vfi = (const float*)d_in[1];
    const float* Wr  = (const float*)d_in[2];
    const float* Wk  = (const float*)d_in[3];
    const float* Wv  = (const float*)d_in[4];
    const float* Wo  = (const float*)d_in[5];
    const float* w0  = (const float*)d_in[6];
    const float* w1  = (const float*)d_in[7];
    const float* w2  = (const float*)d_in[8];
    const float* a0  = (const float*)d_in[9];
    const float* a1  = (const float*)d_in[10];
    const float* a2  = (const float*)d_in[11];
    const float* v0  = (const float*)d_in[12];
    const float* v1  = (const float*)d_in[13];
    const float* v2  = (const float*)d_in[14];
    const float* g1  = (const float*)d_in[15];
    const float* g2  = (const float*)d_in[16];
    const float* rk  = (const float*)d_in[17];
    const float* rnw = (const float*)d_in[18];
    const float* knw = (const float*)d_in[19];

    float* ws = (float*)d_ws;
    size_t o = 0;
    float* RRAW = ws + o; o += (size_t)MT * 1024;  // r; later aliased as SST
    float* KRAW = ws + o; o += (size_t)MT * 512;
    float* VRAW = ws + o; o += (size_t)MT * 512;
    float* XW1  = ws + o; o += (size_t)MT * 64;
    float* XA1  = ws + o; o += (size_t)MT * 64;
    float* XV1  = ws + o; o += (size_t)MT * 32;
    float* XG1  = ws + o; o += (size_t)MT * 160;
    float* DEC  = ws + o; o += (size_t)MT * 1024;
    float* AARR = ws + o; o += (size_t)MT * 1024;
    float* GARR = ws + o; o += (size_t)MT * 1024;
    float* VFIN = ws + o; o += (size_t)MT * 1024;
    float* YARR = ws + o; o += (size_t)MT * 1024;  // y0 from pass1
    float* COS  = ws + o; o += (size_t)Tt * 32;
    float* SIN  = ws + o; o += (size_t)Tt * 32;
    float* ABUF = ws + o; o += (size_t)MT * 512;
    float* QBUF = ws + o; o += (size_t)MT * 1024;
    float* PLB  = ws + o; o += (size_t)1024 * 4096;
    float* ZLB  = ws + o; o += (size_t)1024 * 4096;
    float* BON  = ws + o; o += (size_t)64 * 1024;
    // bf16 buffers (counted in float slots: 1 float = 2 bf16)
    uint16_t* XB  = (uint16_t*)(ws + o); o += (size_t)MT * 512;   // x bf16 [4096][1024]
    uint16_t* WrT = (uint16_t*)(ws + o); o += (size_t)1024 * 512; // [1024][1024]
    uint16_t* WkT = (uint16_t*)(ws + o); o += (size_t)512 * 512;  // [512][1024]
    uint16_t* WvT = (uint16_t*)(ws + o); o += (size_t)512 * 512;
    uint16_t* WoT = (uint16_t*)(ws + o); o += (size_t)1024 * 512;
    uint16_t* w1T = (uint16_t*)(ws + o); o += (size_t)64 * 512;   // [64][1024]
    uint16_t* a1T = (uint16_t*)(ws + o); o += (size_t)64 * 512;
    uint16_t* v1T = (uint16_t*)(ws + o); o += (size_t)32 * 512;
    uint16_t* g1T = (uint16_t*)(ws + o); o += (size_t)160 * 512;
    float* SST = RRAW;          // alias: RRAW dead after pass1
    uint16_t* YB = XB;          // alias: XB dead after stage-1 GEMMs

    rope_table_kernel<<<dim3(Tt), dim3(32), 0, stream>>>(COS, SIN);

    // convert x -> bf16; transpose+convert weights
    f32_to_bf16_kernel<<<dim3((MT * 1024 / 4 + 255) / 256), dim3(256), 0, stream>>>(x, XB, MT * 1024 / 4);
    transpose_bf16_kernel<<<dim3(32, 32), dim3(256), 0, stream>>>(Wr, WrT, 1024, 1024);
    transpose_bf16_kernel<<<dim3(16, 32), dim3(256), 0, stream>>>(Wk, WkT, 1024, 512);
    transpose_bf16_kernel<<<dim3(16, 32), dim3(256), 0, stream>>>(Wv, WvT, 1024, 512);
    transpose_bf16_kernel<<<dim3(32, 32), dim3(256), 0, stream>>>(Wo, WoT, 1024, 1024);
    transpose_bf16_kernel<<<dim3(2, 32),  dim3(256), 0, stream>>>(w1, w1T, 1024, 64);
    transpose_bf16_kernel<<<dim3(2, 32),  dim3(256), 0, stream>>>(a1, a1T, 1024, 64);
    transpose_bf16_kernel<<<dim3(1, 32),  dim3(256), 0, stream>>>(v1, v1T, 1024, 32);
    transpose_bf16_kernel<<<dim3(5, 32),  dim3(256), 0, stream>>>(g1, g1T, 1024, 160);

    dim3 blk(256);
    auto mgrid = [](int N) { return dim3((N + 127) / 128, MT / 128); };
    auto grid  = [](int N) { return dim3((N + 63) / 64, MT / 64); };

    // stage 1: projections from x (bf16 MFMA)
    gemm_bf16<<<mgrid(1024), blk, 0, stream>>>(XB, WrT, RRAW, MT, 1024, 1024, 0);
    gemm_bf16<<<mgrid(512),  blk, 0, stream>>>(XB, WkT, KRAW, MT, 512,  1024, 0);
    gemm_bf16<<<mgrid(512),  blk, 0, stream>>>(XB, WvT, VRAW, MT, 512,  1024, 0);
    gemm_bf16<<<mgrid(64),   blk, 0, stream>>>(XB, w1T, XW1,  MT, 64,   1024, 1);
    gemm_bf16<<<mgrid(64),   blk, 0, stream>>>(XB, a1T, XA1,  MT, 64,   1024, 0);
    gemm_bf16<<<mgrid(32),   blk, 0, stream>>>(XB, v1T, XV1,  MT, 32,   1024, 0);
    gemm_bf16<<<mgrid(160),  blk, 0, stream>>>(XB, g1T, XG1,  MT, 160,  1024, 2);

    // stage 2: LoRA second matmuls with fused epilogues (fp32, small K)
    gemm_f32<<<grid(1024), blk, 0, stream>>>(XW1, w2, DEC,  MT, 1024, 64,  4, w0, nullptr, nullptr);
    gemm_f32<<<grid(1024), blk, 0, stream>>>(XA1, a2, AARR, MT, 1024, 64,  3, a0, nullptr, nullptr);
    gemm_f32<<<grid(1024), blk, 0, stream>>>(XV1, v2, VFIN, MT, 1024, 32,  5, v0, VRAW, vfi);
    gemm_f32<<<grid(1024), blk, 0, stream>>>(XG1, g2, GARR, MT, 1024, 160, 0, nullptr, nullptr, nullptr);

    // stage 3: per-head RMS norm + RoPE (in place)
    normrope_kernel<<<dim3(MT * Hh),   dim3(64), 0, stream>>>(RRAW, rnw, COS, SIN, Hh);
    normrope_kernel<<<dim3(MT * HKVn), dim3(64), 0, stream>>>(KRAW, knw, COS, SIN, HKVn);

    // stage 4: hoist reductions out of the scan
    prep_ab<<<dim3(MT * HKVn), dim3(64), 0, stream>>>(KRAW, RRAW, AARR, ABUF, rk, BON);

    // stage 5: chunk-parallel WKV scan
    wkv_pass1<<<dim3(Bb * Hh * NC), dim3(64), 0, stream>>>(
        RRAW, KRAW, ABUF, AARR, DEC, VFIN, QBUF, YARR, PLB, ZLB);
    wkv_pass2<<<dim3(Bb * Hh), dim3(64), 0, stream>>>(PLB, ZLB, SST);
    wkv_pass3<<<dim3(Bb * Hh * NC), dim3(64), 0, stream>>>(SST, QBUF, VFIN, GARR, BON, YARR, YB);

    // stage 6: out = (y*g) @ Wo (bf16 MFMA)
    gemm_bf16<<<mgrid(1024), blk, 0, stream>>>(YB, WoT, (float*)d_out, MT, 1024, 1024, 0);

    // stage 7: second tuple output = v_first (unchanged)
    copy4_kernel<<<dim3((MT * 1024 / 4 + 255) / 256), dim3(256), 0, stream>>>(
        (const float4*)vfi, (float4*)((float*)d_out + (size_t)MT * 1024), MT * 1024 / 4);
}

// Round 4
// 600.201 us; speedup vs baseline: 3.5870x; 1.2488x over previous
//
#include <hip/hip_runtime.h>
#include <math.h>
#include <stdint.h>

// Problem constants
#define Bb   4
#define Tt   1024
#define Cc   1024
#define Hh   16
#define HKVn 8
#define Nn   64
#define MT   (Bb*Tt)
#define NC   16      // chunks per sequence
#define CL   64      // chunk length
#define NCAT 2368    // 1024+512+512+64+64+32+160

typedef __bf16 bf16x8_t __attribute__((ext_vector_type(8)));
typedef float  f32x4_t  __attribute__((ext_vector_type(4)));

__device__ __forceinline__ uint16_t f2bf(float f) {
    uint32_t u = __float_as_uint(f);
    uint32_t r = (u + 0x7fffu + ((u >> 16) & 1u)) >> 16;
    return (uint16_t)r;
}

// ---------------------------------------------------------------------------
// RoPE cos/sin table: [T][32]
// ---------------------------------------------------------------------------
__global__ void rope_table_kernel(float* __restrict__ cost, float* __restrict__ sint) {
    int t = blockIdx.x;
    int i = threadIdx.x; // 0..31
    float invf = powf(1.0e6f, -(float)i / 32.0f);
    float f = (float)t * invf;
    cost[t * 32 + i] = cosf(f);
    sint[t * 32 + i] = sinf(f);
}

// ---------------------------------------------------------------------------
// fp32 -> bf16 flat convert (n multiple of 4)
// ---------------------------------------------------------------------------
__global__ __launch_bounds__(256) void f32_to_bf16_kernel(
    const float* __restrict__ in, uint16_t* __restrict__ out, int n4)
{
    int i = blockIdx.x * blockDim.x + threadIdx.x;
    if (i >= n4) return;
    float4 v = reinterpret_cast<const float4*>(in)[i];
    ushort4 o;
    o.x = f2bf(v.x); o.y = f2bf(v.y); o.z = f2bf(v.z); o.w = f2bf(v.w);
    reinterpret_cast<ushort4*>(out)[i] = o;
}

// ---------------------------------------------------------------------------
// All weight transposes in one launch. z selects the weight; all have K=1024
// source rows. Outputs: WCAT rows [off, off+N) for z<7, WoT for z=7.
// ---------------------------------------------------------------------------
__global__ __launch_bounds__(256) void transpose_all_kernel(
    const float* __restrict__ Wr, const float* __restrict__ Wk, const float* __restrict__ Wv,
    const float* __restrict__ w1, const float* __restrict__ a1, const float* __restrict__ v1,
    const float* __restrict__ g1, const float* __restrict__ Wo,
    uint16_t* __restrict__ WCAT, uint16_t* __restrict__ WoT)
{
    int z = blockIdx.z;
    const float* W; int N; int off; uint16_t* out;
    switch (z) {
        case 0: W = Wr; N = 1024; off = 0;    out = WCAT; break;
        case 1: W = Wk; N = 512;  off = 1024; out = WCAT; break;
        case 2: W = Wv; N = 512;  off = 1536; out = WCAT; break;
        case 3: W = w1; N = 64;   off = 2048; out = WCAT; break;
        case 4: W = a1; N = 64;   off = 2112; out = WCAT; break;
        case 5: W = v1; N = 32;   off = 2176; out = WCAT; break;
        case 6: W = g1; N = 160;  off = 2208; out = WCAT; break;
        default: W = Wo; N = 1024; off = 0;   out = WoT;  break;
    }
    int n0 = blockIdx.x * 32, k0 = blockIdx.y * 32;
    if (n0 >= N) return;
    __shared__ float tile[32][33];
    int tx = threadIdx.x & 31, ty = threadIdx.x >> 5; // 32 x 8
    #pragma unroll
    for (int i = 0; i < 32; i += 8) {
        int k = k0 + ty + i, n = n0 + tx;
        tile[ty + i][tx] = (n < N) ? W[(size_t)k * N + n] : 0.f;
    }
    __syncthreads();
    #pragma unroll
    for (int i = 0; i < 32; i += 8) {
        int n = n0 + ty + i, k = k0 + tx;
        if (n < N) out[(size_t)(off + n) * 1024 + k] = f2bf(tile[tx][ty + i]);
    }
}

// ---------------------------------------------------------------------------
// Fused stage-1 projection GEMM: C[M][2368] = XB[M][1024] @ WCAT^T, with the
// per-column-segment epilogue scattering into 7 output buffers.
// 128x128 tile, BK=64, 4 waves, 16x16x32 MFMA, global_load_lds + XOR swizzle.
// ---------------------------------------------------------------------------
__global__ __launch_bounds__(256) void gemm_bf16_proj(
    const uint16_t* __restrict__ A, const uint16_t* __restrict__ Bt,
    int M, int N, int K,
    float* __restrict__ R_, float* __restrict__ K_, float* __restrict__ V_,
    float* __restrict__ W1, float* __restrict__ A1, float* __restrict__ V1,
    float* __restrict__ G1)
{
    __shared__ __align__(16) uint16_t As[128 * 64];
    __shared__ __align__(16) uint16_t Bs[128 * 64];
    int tid  = threadIdx.x;
    int lane = tid & 63, wid = tid >> 6;
    int wm = (wid >> 1) * 64, wn = (wid & 1) * 64;
    int bm = blockIdx.y * 128, bn = blockIdx.x * 128;

    f32x4_t acc[4][4];
    #pragma unroll
    for (int i = 0; i < 4; ++i)
        #pragma unroll
        for (int j = 0; j < 4; ++j)
            #pragma unroll
            for (int e = 0; e < 4; ++e) acc[i][j][e] = 0.f;

    int rowS[4], kbS[4];
    #pragma unroll
    for (int i = 0; i < 4; ++i) {
        int d = (i * 256 + tid) * 16;
        int row = d >> 7;
        int kb = (d & 127) ^ ((row & 7) << 4);
        rowS[i] = row; kbS[i] = kb >> 1;
    }

    for (int k0 = 0; k0 < K; k0 += 64) {
        #pragma unroll
        for (int i = 0; i < 4; ++i) {
            const uint16_t* srcA = A + (size_t)(bm + rowS[i]) * K + k0 + kbS[i];
            uint16_t* ldsA = As + (i * 256 + wid * 64) * 8;
            __builtin_amdgcn_global_load_lds(
                (const __attribute__((address_space(1))) uint32_t*)srcA,
                (__attribute__((address_space(3))) uint32_t*)ldsA, 16, 0, 0);
            int nr = bn + rowS[i];
            const uint16_t* srcB = Bt + (size_t)(nr < N ? nr : 0) * K + k0 + kbS[i];
            uint16_t* ldsB = Bs + (i * 256 + wid * 64) * 8;
            __builtin_amdgcn_global_load_lds(
                (const __attribute__((address_space(1))) uint32_t*)srcB,
                (__attribute__((address_space(3))) uint32_t*)ldsB, 16, 0, 0);
        }
        __syncthreads();

        #pragma unroll
        for (int kk = 0; kk < 64; kk += 32) {
            int fb = (kk + ((lane >> 4) << 3)) << 1;
            bf16x8_t af[4], bfr[4];
            #pragma unroll
            for (int i = 0; i < 4; ++i) {
                int row = wm + i * 16 + (lane & 15);
                int byteA = (row << 7) + (fb ^ ((row & 7) << 4));
                af[i] = *reinterpret_cast<const bf16x8_t*>(
                    reinterpret_cast<const char*>(As) + byteA);
                int col = wn + i * 16 + (lane & 15);
                int byteB = (col << 7) + (fb ^ ((col & 7) << 4));
                bfr[i] = *reinterpret_cast<const bf16x8_t*>(
                    reinterpret_cast<const char*>(Bs) + byteB);
            }
            #pragma unroll
            for (int i = 0; i < 4; ++i)
                #pragma unroll
                for (int j = 0; j < 4; ++j)
                    acc[i][j] = __builtin_amdgcn_mfma_f32_16x16x32_bf16(
                        af[i], bfr[j], acc[i][j], 0, 0, 0);
        }
        __syncthreads();
    }

    #pragma unroll
    for (int i = 0; i < 4; ++i) {
        int row0 = bm + wm + i * 16 + ((lane >> 4) << 2);
        #pragma unroll
        for (int j = 0; j < 4; ++j) {
            int col = bn + wn + j * 16 + (lane & 15);
            if (col >= N) continue;
            #pragma unroll
            for (int rg = 0; rg < 4; ++rg) {
                float v = acc[i][j][rg];
                int row = row0 + rg;
                if (col < 1024)       R_[(size_t)row * 1024 + col] = v;
                else if (col < 1536)  K_[(size_t)row * 512 + (col - 1024)] = v;
                else if (col < 2048)  V_[(size_t)row * 512 + (col - 1536)] = v;
                else if (col < 2112)  W1[(size_t)row * 64 + (col - 2048)] = tanhf(v);
                else if (col < 2176)  A1[(size_t)row * 64 + (col - 2112)] = v;
                else if (col < 2208)  V1[(size_t)row * 32 + (col - 2176)] = v;
                else                  G1[(size_t)row * 160 + (col - 2208)] = 1.f / (1.f + expf(-v));
            }
        }
    }
}

// ---------------------------------------------------------------------------
// bf16 MFMA GEMM (plain epilogue) for the output projection.
// ---------------------------------------------------------------------------
__global__ __launch_bounds__(256) void gemm_bf16(
    const uint16_t* __restrict__ A, const uint16_t* __restrict__ Bt,
    float* __restrict__ C, int M, int N, int K)
{
    __shared__ __align__(16) uint16_t As[128 * 64];
    __shared__ __align__(16) uint16_t Bs[128 * 64];
    int tid  = threadIdx.x;
    int lane = tid & 63, wid = tid >> 6;
    int wm = (wid >> 1) * 64, wn = (wid & 1) * 64;
    int bm = blockIdx.y * 128, bn = blockIdx.x * 128;

    f32x4_t acc[4][4];
    #pragma unroll
    for (int i = 0; i < 4; ++i)
        #pragma unroll
        for (int j = 0; j < 4; ++j)
            #pragma unroll
            for (int e = 0; e < 4; ++e) acc[i][j][e] = 0.f;

    int rowS[4], kbS[4];
    #pragma unroll
    for (int i = 0; i < 4; ++i) {
        int d = (i * 256 + tid) * 16;
        int row = d >> 7;
        int kb = (d & 127) ^ ((row & 7) << 4);
        rowS[i] = row; kbS[i] = kb >> 1;
    }

    for (int k0 = 0; k0 < K; k0 += 64) {
        #pragma unroll
        for (int i = 0; i < 4; ++i) {
            const uint16_t* srcA = A + (size_t)(bm + rowS[i]) * K + k0 + kbS[i];
            uint16_t* ldsA = As + (i * 256 + wid * 64) * 8;
            __builtin_amdgcn_global_load_lds(
                (const __attribute__((address_space(1))) uint32_t*)srcA,
                (__attribute__((address_space(3))) uint32_t*)ldsA, 16, 0, 0);
            int nr = bn + rowS[i];
            const uint16_t* srcB = Bt + (size_t)(nr < N ? nr : 0) * K + k0 + kbS[i];
            uint16_t* ldsB = Bs + (i * 256 + wid * 64) * 8;
            __builtin_amdgcn_global_load_lds(
                (const __attribute__((address_space(1))) uint32_t*)srcB,
                (__attribute__((address_space(3))) uint32_t*)ldsB, 16, 0, 0);
        }
        __syncthreads();

        #pragma unroll
        for (int kk = 0; kk < 64; kk += 32) {
            int fb = (kk + ((lane >> 4) << 3)) << 1;
            bf16x8_t af[4], bfr[4];
            #pragma unroll
            for (int i = 0; i < 4; ++i) {
                int row = wm + i * 16 + (lane & 15);
                int byteA = (row << 7) + (fb ^ ((row & 7) << 4));
                af[i] = *reinterpret_cast<const bf16x8_t*>(
                    reinterpret_cast<const char*>(As) + byteA);
                int col = wn + i * 16 + (lane & 15);
                int byteB = (col << 7) + (fb ^ ((col & 7) << 4));
                bfr[i] = *reinterpret_cast<const bf16x8_t*>(
                    reinterpret_cast<const char*>(Bs) + byteB);
            }
            #pragma unroll
            for (int i = 0; i < 4; ++i)
                #pragma unroll
                for (int j = 0; j < 4; ++j)
                    acc[i][j] = __builtin_amdgcn_mfma_f32_16x16x32_bf16(
                        af[i], bfr[j], acc[i][j], 0, 0, 0);
        }
        __syncthreads();
    }

    #pragma unroll
    for (int i = 0; i < 4; ++i) {
        int row0 = bm + wm + i * 16 + ((lane >> 4) << 2);
        #pragma unroll
        for (int j = 0; j < 4; ++j) {
            int col = bn + wn + j * 16 + (lane & 15);
            if (col >= N) continue;
            #pragma unroll
            for (int rg = 0; rg < 4; ++rg)
                C[(size_t)(row0 + rg) * N + col] = acc[i][j][rg];
        }
    }
}

// ---------------------------------------------------------------------------
// Fused stage-2 LoRA GEMMs: one launch, 4 segments (seg = blockIdx.x>>4).
//   seg 0: DEC  = exp(-exp(-softplus(-(XW1@w2 + w0)) - 0.5))   K=64
//   seg 1: AARR = sigmoid(XA1@a2 + a0)                         K=64
//   seg 2: VFIN = vmix(sigmoid(XV1@v2 + v0), VRAW, vfi)        K=32
//   seg 3: GARR = XG1@g2                                       K=160
// All outputs [MT][1024].
// ---------------------------------------------------------------------------
__global__ __launch_bounds__(256) void lora2_fused(
    const float* __restrict__ XW1, const float* __restrict__ XA1,
    const float* __restrict__ XV1, const float* __restrict__ XG1,
    const float* __restrict__ w2, const float* __restrict__ a2,
    const float* __restrict__ v2, const float* __restrict__ g2,
    const float* __restrict__ w0, const float* __restrict__ a0, const float* __restrict__ v0,
    const float* __restrict__ VRAW, const float* __restrict__ vfi,
    float* __restrict__ DEC, float* __restrict__ AARR,
    float* __restrict__ VFIN, float* __restrict__ GARR)
{
    int seg = blockIdx.x >> 4;
    int bn = (blockIdx.x & 15) * 64;
    int bm = blockIdx.y * 64;

    const float* A; const float* Bm; const float* bias; float* C; int K;
    if (seg == 0)      { A = XW1; Bm = w2; bias = w0; C = DEC;  K = 64; }
    else if (seg == 1) { A = XA1; Bm = a2; bias = a0; C = AARR; K = 64; }
    else if (seg == 2) { A = XV1; Bm = v2; bias = v0; C = VFIN; K = 32; }
    else               { A = XG1; Bm = g2; bias = nullptr; C = GARR; K = 160; }

    __shared__ float As[16][65];
    __shared__ float Bs[16][68];
    int tid = threadIdx.x;
    int tx = tid & 15, ty = tid >> 4;
    int am = tid >> 2, ak = (tid & 3) << 2;
    int bk = tid >> 4, bn4 = (tid & 15) << 2;

    float acc[4][4] = {};

    for (int k0 = 0; k0 < K; k0 += 16) {
        float4 av = *reinterpret_cast<const float4*>(&A[(size_t)(bm + am) * K + k0 + ak]);
        As[ak + 0][am] = av.x; As[ak + 1][am] = av.y;
        As[ak + 2][am] = av.z; As[ak + 3][am] = av.w;

        float4 bv = *reinterpret_cast<const float4*>(&Bm[(size_t)(k0 + bk) * 1024 + bn + bn4]);
        *reinterpret_cast<float4*>(&Bs[bk][bn4]) = bv;

        __syncthreads();
        #pragma unroll
        for (int kk = 0; kk < 16; ++kk) {
            float a_[4], b_[4];
            #pragma unroll
            for (int i = 0; i < 4; ++i) a_[i] = As[kk][ty * 4 + i];
            #pragma unroll
            for (int j = 0; j < 4; ++j) b_[j] = Bs[kk][tx * 4 + j];
            #pragma unroll
            for (int i = 0; i < 4; ++i)
                #pragma unroll
                for (int j = 0; j < 4; ++j)
                    acc[i][j] = fmaf(a_[i], b_[j], acc[i][j]);
        }
        __syncthreads();
    }

    #pragma unroll
    for (int i = 0; i < 4; ++i) {
        int row = bm + ty * 4 + i;
        #pragma unroll
        for (int j = 0; j < 4; ++j) {
            int col = bn + tx * 4 + j;
            float v = acc[i][j];
            if (seg == 0) {
                float z = v + bias[col];
                float t2 = -z;
                float sp = (t2 > 20.f) ? t2 : log1pf(expf(t2));
                v = expf(-expf(-sp - 0.5f));
            } else if (seg == 1) {
                v = 1.f / (1.f + expf(-(v + bias[col])));
            } else if (seg == 2) {
                float m = 1.f / (1.f + expf(-(v + bias[col])));
                float vr = VRAW[(size_t)row * 512 + ((col >> 7) << 6) + (col & 63)];
                float vf = vfi[(size_t)row * 1024 + col];
                v = vr + (vf - vr) * m;
            }
            C[(size_t)row * 1024 + col] = v;
        }
    }
}

// ---------------------------------------------------------------------------
// Per-(b,t,head) RMS-norm over N=64 + RoPE, in place. One wave per block.
// ---------------------------------------------------------------------------
__global__ __launch_bounds__(64) void normrope_kernel(
    float* __restrict__ data, const float* __restrict__ nw,
    const float* __restrict__ cost, const float* __restrict__ sint, int nh)
{
    int bt = blockIdx.x / nh;
    int h  = blockIdx.x % nh;
    int t  = bt & (Tt - 1);
    int lane = threadIdx.x;
    size_t idx = ((size_t)bt * nh + h) * 64 + lane;

    float x = data[idx];
    float ss = x * x;
    #pragma unroll
    for (int m = 1; m < 64; m <<= 1) ss += __shfl_xor(ss, m, 64);
    float xn = x * rsqrtf(ss * (1.f / 64.f) + 1e-6f) * nw[lane];

    float partner = __shfl_xor(xn, 32, 64);
    int fi = lane & 31;
    float c = cost[t * 32 + fi], s = sint[t * 32 + fi];
    float rot = (lane < 32) ? -partner : partner;
    data[idx] = fmaf(xn, c, rot * s);
}

// ---------------------------------------------------------------------------
// prep_ab: hoist state-independent reductions out of the scan.
// ---------------------------------------------------------------------------
__global__ __launch_bounds__(64) void prep_ab(
    const float* __restrict__ Kv, const float* __restrict__ R,
    float* __restrict__ Aio, float* __restrict__ Ab,
    const float* __restrict__ rk, float* __restrict__ BON)
{
    int blk = blockIdx.x;      // bt*8 + hk
    int hk = blk & 7;
    int bt = blk >> 3;
    int b = bt >> 10, t = bt & 1023;
    int lane = threadIdx.x;

    size_t kidx = ((size_t)bt * 8 + hk) * 64 + lane;
    float k = Kv[kidx];
    float ss = k * k;
    #pragma unroll
    for (int m = 1; m < 64; m <<= 1) ss += __shfl_xor(ss, m, 64);
    float kk = k / fmaxf(sqrtf(ss), 1e-12f);
    Ab[kidx] = -kk;

    #pragma unroll
    for (int rep = 0; rep < 2; ++rep) {
        int h = hk * 2 + rep;
        size_t cidx = (size_t)bt * 1024 + h * 64 + lane;
        float asig = Aio[cidx];
        Aio[cidx] = kk * asig;
        float r = R[cidx];
        float bon = r * k * rk[h * 64 + lane];
        #pragma unroll
        for (int m = 1; m < 64; m <<= 1) bon += __shfl_xor(bon, m, 64);
        if (lane == 0) BON[((size_t)(b * 16 + h)) * 1024 + t] = bon;
    }
}

// ---------------------------------------------------------------------------
// wkv_pass1: per-chunk zero-state scan. 2 waves per block: wave0 owns the
// transition product P, wave1 owns the zero-init state Z. Broadcast operands
// (a,b,d,k,r) are wave-uniform -> read directly from global (scalar loads),
// no LDS, no barriers.
// ---------------------------------------------------------------------------
__global__ __launch_bounds__(128) void wkv_pass1(
    const float* __restrict__ R, const float* __restrict__ Kv,
    const float* __restrict__ Ab, const float* __restrict__ Bhat,
    const float* __restrict__ Dd, const float* __restrict__ Vv,
    float* __restrict__ Q, float* __restrict__ Y0,
    float* __restrict__ PL, float* __restrict__ ZL)
{
    int blk = blockIdx.x;           // (b*16+h)*16 + c
    int c   = blk & 15;
    int bh  = blk >> 4;
    int h   = bh & 15;
    int b   = bh >> 4;
    int hk  = h >> 1;
    int tid = threadIdx.x, lane = tid & 63, wv = tid >> 6;
    int t0 = c * CL;

    size_t cb = ((size_t)(b * 1024 + t0)) * 1024 + h * 64;
    size_t kb = ((size_t)(b * 1024 + t0)) * 512 + hk * 64;
    size_t qb = (((size_t)bh) * 1024 + t0) * 64;
    size_t pb = ((size_t)blk) * 4096 + (size_t)lane * 64;

    float S[64];

    if (wv == 0) {
        // ---- P wave: P <- P*diag(d) + (P.a) b^T ; q = P.r ----
        #pragma unroll
        for (int j = 0; j < 64; ++j) S[j] = (j == lane) ? 1.f : 0.f;

        for (int u = 0; u < CL; ++u) {
            const float* ap = Ab   + kb + (size_t)u * 512;
            const float* bp = Bhat + cb + (size_t)u * 1024;
            const float* dp = Dd   + cb + (size_t)u * 1024;
            const float* rp = R    + cb + (size_t)u * 1024;

            float pa0 = 0.f, pa1 = 0.f, pa2 = 0.f, pa3 = 0.f;
            #pragma unroll
            for (int j = 0; j < 64; j += 4) {
                pa0 = fmaf(S[j + 0], ap[j + 0], pa0);
                pa1 = fmaf(S[j + 1], ap[j + 1], pa1);
                pa2 = fmaf(S[j + 2], ap[j + 2], pa2);
                pa3 = fmaf(S[j + 3], ap[j + 3], pa3);
            }
            float pa = (pa0 + pa1) + (pa2 + pa3);

            float q0 = 0.f, q1 = 0.f, q2 = 0.f, q3 = 0.f;
            #pragma unroll
            for (int j = 0; j < 64; j += 4) {
                S[j + 0] = fmaf(S[j + 0], dp[j + 0], pa * bp[j + 0]); q0 = fmaf(S[j + 0], rp[j + 0], q0);
                S[j + 1] = fmaf(S[j + 1], dp[j + 1], pa * bp[j + 1]); q1 = fmaf(S[j + 1], rp[j + 1], q1);
                S[j + 2] = fmaf(S[j + 2], dp[j + 2], pa * bp[j + 2]); q2 = fmaf(S[j + 2], rp[j + 2], q2);
                S[j + 3] = fmaf(S[j + 3], dp[j + 3], pa * bp[j + 3]); q3 = fmaf(S[j + 3], rp[j + 3], q3);
            }
            Q[qb + (size_t)u * 64 + lane] = (q0 + q1) + (q2 + q3);
        }
        #pragma unroll
        for (int j = 0; j < 64; j += 4)
            *reinterpret_cast<float4*>(&PL[pb + j]) =
                make_float4(S[j], S[j + 1], S[j + 2], S[j + 3]);
    } else {
        // ---- Z wave: Z <- Z*diag(d) + (Z.a) b^T + v k^T ; y0 = Z.r ----
        #pragma unroll
        for (int j = 0; j < 64; ++j) S[j] = 0.f;

        for (int u = 0; u < CL; ++u) {
            const float* ap = Ab   + kb + (size_t)u * 512;
            const float* bp = Bhat + cb + (size_t)u * 1024;
            const float* dp = Dd   + cb + (size_t)u * 1024;
            const float* rp = R    + cb + (size_t)u * 1024;
            const float* kp = Kv   + kb + (size_t)u * 512;
            float v = Vv[cb + (size_t)u * 1024 + lane];

            float za0 = 0.f, za1 = 0.f, za2 = 0.f, za3 = 0.f;
            #pragma unroll
            for (int j = 0; j < 64; j += 4) {
                za0 = fmaf(S[j + 0], ap[j + 0], za0);
                za1 = fmaf(S[j + 1], ap[j + 1], za1);
                za2 = fmaf(S[j + 2], ap[j + 2], za2);
                za3 = fmaf(S[j + 3], ap[j + 3], za3);
            }
            float za = (za0 + za1) + (za2 + za3);

            float y0 = 0.f, y1 = 0.f, y2 = 0.f, y3 = 0.f;
            #pragma unroll
            for (int j = 0; j < 64; j += 4) {
                S[j + 0] = fmaf(S[j + 0], dp[j + 0], fmaf(za, bp[j + 0], v * kp[j + 0])); y0 = fmaf(S[j + 0], rp[j + 0], y0);
                S[j + 1] = fmaf(S[j + 1], dp[j + 1], fmaf(za, bp[j + 1], v * kp[j + 1])); y1 = fmaf(S[j + 1], rp[j + 1], y1);
                S[j + 2] = fmaf(S[j + 2], dp[j + 2], fmaf(za, bp[j + 2], v * kp[j + 2])); y2 = fmaf(S[j + 2], rp[j + 2], y2);
                S[j + 3] = fmaf(S[j + 3], dp[j + 3], fmaf(za, bp[j + 3], v * kp[j + 3])); y3 = fmaf(S[j + 3], rp[j + 3], y3);
            }
            Y0[cb + (size_t)u * 1024 + lane] = (y0 + y1) + (y2 + y3);
        }
        #pragma unroll
        for (int j = 0; j < 64; j += 4)
            *reinterpret_cast<float4*>(&ZL[pb + j]) =
                make_float4(S[j], S[j + 1], S[j + 2], S[j + 3]);
    }
}

// ---------------------------------------------------------------------------
// wkv_pass2: sequential chunk-state propagation, 4 waves per block.
// Lane = row, wave = 16-column slice. S <- S @ P_c + Z_c per chunk.
// ---------------------------------------------------------------------------
__global__ __launch_bounds__(256) void wkv_pass2(
    const float* __restrict__ PL, const float* __restrict__ ZL, float* __restrict__ SST)
{
    int bh = blockIdx.x;
    int tid = threadIdx.x, lane = tid & 63, wv = tid >> 6;
    int j0 = wv * 16;
    __shared__ float Sld[64][65];
    __shared__ __align__(16) float Pld[64][68];

    #pragma unroll
    for (int j = 0; j < 16; ++j) Sld[lane][j0 + j] = 0.f;
    __syncthreads();

    for (int cc = 0; cc < NC; ++cc) {
        size_t base = (((size_t)bh) * NC + cc) * 4096 + (size_t)lane * 64 + j0;
        #pragma unroll
        for (int jc = 0; jc < 4; ++jc)
            *reinterpret_cast<float4*>(&SST[base + jc * 4]) =
                make_float4(Sld[lane][j0 + jc*4], Sld[lane][j0 + jc*4 + 1],
                            Sld[lane][j0 + jc*4 + 2], Sld[lane][j0 + jc*4 + 3]);
        if (cc == NC - 1) break;

        #pragma unroll
        for (int jc = 0; jc < 4; ++jc) {
            float4 p4 = *reinterpret_cast<const float4*>(&PL[base + jc * 4]);
            *reinterpret_cast<float4*>(&Pld[lane][j0 + jc * 4]) = p4;
        }
        float acc[16];
        #pragma unroll
        for (int jc = 0; jc < 4; ++jc) {
            float4 z4 = *reinterpret_cast<const float4*>(&ZL[base + jc * 4]);
            acc[jc*4+0] = z4.x; acc[jc*4+1] = z4.y; acc[jc*4+2] = z4.z; acc[jc*4+3] = z4.w;
        }
        __syncthreads();

        for (int m = 0; m < 64; ++m) {
            float sm = Sld[lane][m];
            #pragma unroll
            for (int jc = 0; jc < 4; ++jc) {
                float4 p4 = *reinterpret_cast<const float4*>(&Pld[m][j0 + jc * 4]);
                acc[jc*4+0] = fmaf(sm, p4.x, acc[jc*4+0]);
                acc[jc*4+1] = fmaf(sm, p4.y, acc[jc*4+1]);
                acc[jc*4+2] = fmaf(sm, p4.z, acc[jc*4+2]);
                acc[jc*4+3] = fmaf(sm, p4.w, acc[jc*4+3]);
            }
        }
        __syncthreads();
        #pragma unroll
        for (int j = 0; j < 16; ++j) Sld[lane][j0 + j] = acc[j];
        __syncthreads();
    }
}

// ---------------------------------------------------------------------------
// wkv_pass3: y = (y0 + Sstart.q + bon*v) * g -> bf16 for the Wo GEMM.
// Uniform q/bon reads from global (no LDS).
// ---------------------------------------------------------------------------
__global__ __launch_bounds__(64) void wkv_pass3(
    const float* __restrict__ SST, const float* __restrict__ Q,
    const float* __restrict__ Vv, const float* __restrict__ G,
    const float* __restrict__ BON, const float* __restrict__ Y0,
    uint16_t* __restrict__ Yb)
{
    int blk = blockIdx.x;   // (b*16+h)*16 + c
    int c = blk & 15, bh = blk >> 4, h = bh & 15, b = bh >> 4;
    int lane = threadIdx.x;
    int t0 = c * CL;

    float S[64];
    size_t sb = ((size_t)blk) * 4096 + (size_t)lane * 64;
    #pragma unroll
    for (int jc = 0; jc < 16; ++jc) {
        float4 s4 = *reinterpret_cast<const float4*>(&SST[sb + jc * 4]);
        S[jc*4+0] = s4.x; S[jc*4+1] = s4.y; S[jc*4+2] = s4.z; S[jc*4+3] = s4.w;
    }

    size_t cb = ((size_t)(b * 1024 + t0)) * 1024 + h * 64 + lane;
    size_t qbase = (((size_t)bh) * 1024 + t0) * 64;
    size_t bb = ((size_t)bh) * 1024 + t0;

    for (int u = 0; u < CL; ++u) {
        const float* qp = Q + qbase + (size_t)u * 64;   // uniform
        float d0 = 0.f, d1 = 0.f, d2 = 0.f, d3 = 0.f;
        #pragma unroll
        for (int j = 0; j < 64; j += 4) {
            d0 = fmaf(S[j + 0], qp[j + 0], d0);
            d1 = fmaf(S[j + 1], qp[j + 1], d1);
            d2 = fmaf(S[j + 2], qp[j + 2], d2);
            d3 = fmaf(S[j + 3], qp[j + 3], d3);
        }
        float dot = (d0 + d1) + (d2 + d3);
        float y0 = Y0[cb + (size_t)u * 1024];
        float vc = Vv[cb + (size_t)u * 1024];
        float gc = G[cb + (size_t)u * 1024];
        float bon = BON[bb + u];
        Yb[cb + (size_t)u * 1024] = f2bf((y0 + dot + bon * vc) * gc);
    }
}

// ---------------------------------------------------------------------------
__global__ void copy4_kernel(const float4* __restrict__ s, float4* __restrict__ d, int n) {
    int i = blockIdx.x * blockDim.x + threadIdx.x;
    if (i < n) d[i] = s[i];
}

// ---------------------------------------------------------------------------
extern "C" void kernel_launch(void* const* d_in, const int* in_sizes, int n_in,
                              void* d_out, int out_size, void* d_ws, size_t ws_size,
                              hipStream_t stream)
{
    const float* x   = (const float*)d_in[0];
    const float* vfi = (const float*)d_in[1];
    const float* Wr  = (const float*)d_in[2];
    const float* Wk  = (const float*)d_in[3];
    const float* Wv  = (const float*)d_in[4];
    const float* Wo  = (const float*)d_in[5];
    const float* w0  = (const float*)d_in[6];
    const float* w1  = (const float*)d_in[7];
    const float* w2  = (const float*)d_in[8];
    const float* a0  = (const float*)d_in[9];
    const float* a1  = (const float*)d_in[10];
    const float* a2  = (const float*)d_in[11];
    const float* v0  = (const float*)d_in[12];
    const float* v1  = (const float*)d_in[13];
    const float* v2  = (const float*)d_in[14];
    const float* g1  = (const float*)d_in[15];
    const float* g2  = (const float*)d_in[16];
    const float* rk  = (const float*)d_in[17];
    const float* rnw = (const float*)d_in[18];
    const float* knw = (const float*)d_in[19];

    float* ws = (float*)d_ws;
    size_t o = 0;
    float* RRAW = ws + o; o += (size_t)MT * 1024;  // r; later aliased as SST
    float* KRAW = ws + o; o += (size_t)MT * 512;
    float* VRAW = ws + o; o += (size_t)MT * 512;
    float* XW1  = ws + o; o += (size_t)MT * 64;
    float* XA1  = ws + o; o += (size_t)MT * 64;
    float* XV1  = ws + o; o += (size_t)MT * 32;
    float* XG1  = ws + o; o += (size_t)MT * 160;
    float* DEC  = ws + o; o += (size_t)MT * 1024;
    float* AARR = ws + o; o += (size_t)MT * 1024;
    float* GARR = ws + o; o += (size_t)MT * 1024;
    float* VFIN = ws + o; o += (size_t)MT * 1024;
    float* YARR = ws + o; o += (size_t)MT * 1024;  // y0 from pass1
    float* COS  = ws + o; o += (size_t)Tt * 32;
    float* SIN  = ws + o; o += (size_t)Tt * 32;
    float* ABUF = ws + o; o += (size_t)MT * 512;
    float* QBUF = ws + o; o += (size_t)MT * 1024;
    float* PLB  = ws + o; o += (size_t)1024 * 4096;
    float* ZLB  = ws + o; o += (size_t)1024 * 4096;
    float* BON  = ws + o; o += (size_t)64 * 1024;
    // bf16 buffers (counted in float slots: 1 float = 2 bf16)
    uint16_t* XB   = (uint16_t*)(ws + o); o += (size_t)MT * 512;    // x bf16 [4096][1024]
    uint16_t* WCAT = (uint16_t*)(ws + o); o += (size_t)NCAT * 512;  // [2368][1024]
    uint16_t* WoT  = (uint16_t*)(ws + o); o += (size_t)1024 * 512;  // [1024][1024]
    float* SST = RRAW;          // alias: RRAW dead after pass1
    uint16_t* YB = XB;          // alias: XB dead after stage-1 GEMM

    rope_table_kernel<<<dim3(Tt), dim3(32), 0, stream>>>(COS, SIN);
    f32_to_bf16_kernel<<<dim3((MT * 1024 / 4 + 255) / 256), dim3(256), 0, stream>>>(x, XB, MT * 1024 / 4);
    transpose_all_kernel<<<dim3(32, 32, 8), dim3(256), 0, stream>>>(
        Wr, Wk, Wv, w1, a1, v1, g1, Wo, WCAT, WoT);

    dim3 blk(256);

    // stage 1: all projections in one bf16 MFMA GEMM (N = 2368)
    gemm_bf16_proj<<<dim3((NCAT + 127) / 128, MT / 128), blk, 0, stream>>>(
        XB, WCAT, MT, NCAT, 1024, RRAW, KRAW, VRAW, XW1, XA1, XV1, XG1);

    // stage 2: all LoRA second matmuls in one launch
    lora2_fused<<<dim3(64, MT / 64), blk, 0, stream>>>(
        XW1, XA1, XV1, XG1, w2, a2, v2, g2, w0, a0, v0, VRAW, vfi,
        DEC, AARR, VFIN, GARR);

    // stage 3: per-head RMS norm + RoPE (in place)
    normrope_kernel<<<dim3(MT * Hh),   dim3(64), 0, stream>>>(RRAW, rnw, COS, SIN, Hh);
    normrope_kernel<<<dim3(MT * HKVn), dim3(64), 0, stream>>>(KRAW, knw, COS, SIN, HKVn);

    // stage 4: hoist reductions out of the scan
    prep_ab<<<dim3(MT * HKVn), dim3(64), 0, stream>>>(KRAW, RRAW, AARR, ABUF, rk, BON);

    // stage 5: chunk-parallel WKV scan
    wkv_pass1<<<dim3(Bb * Hh * NC), dim3(128), 0, stream>>>(
        RRAW, KRAW, ABUF, AARR, DEC, VFIN, QBUF, YARR, PLB, ZLB);
    wkv_pass2<<<dim3(Bb * Hh), dim3(256), 0, stream>>>(PLB, ZLB, SST);
    wkv_pass3<<<dim3(Bb * Hh * NC), dim3(64), 0, stream>>>(
        SST, QBUF, VFIN, GARR, BON, YARR, YB);

    // stage 6: out = (y*g) @ Wo (bf16 MFMA)
    gemm_bf16<<<dim3(1024 / 128, MT / 128), blk, 0, stream>>>(
        YB, WoT, (float*)d_out, MT, 1024, 1024);

    // stage 7: second tuple output = v_first (unchanged)
    copy4_kernel<<<dim3((MT * 1024 / 4 + 255) / 256), dim3(256), 0, stream>>>(
        (const float4*)vfi, (float4*)((float*)d_out + (size_t)MT * 1024), MT * 1024 / 4);
}